// Round 7
// baseline (486.063 us; speedup 1.0000x reference)
//
#include <hip/hip_runtime.h>
#include <hip/hip_bf16.h>

#define NFEAT 128
#define EPB   4096          // edges per A-block (16 per thread * 256)
#define RPB   256           // rows per bucket (bucket = row >> 8)
#define NBU_PAD 512
#define BCAP  6144          // bucket capacity in pass B (mean ~4092, +32 sigma)

typedef short bf16x8 __attribute__((ext_vector_type(8)));
typedef float f32x4  __attribute__((ext_vector_type(4)));

// ---------- Pass A1: per-block bucket histogram (LDS), coalesced write ----------
__global__ __launch_bounds__(256) void a1_hist(const int* __restrict__ rows, int E,
                                               int* __restrict__ countsT, int nbu) {
    __shared__ int h[NBU_PAD];
    int t = threadIdx.x;
    for (int i = t; i < NBU_PAD; i += 256) h[i] = 0;
    __syncthreads();
    int e0 = blockIdx.x * EPB;
    int ecnt = min(EPB, E - e0);
    for (int k = t; k < ecnt; k += 256) atomicAdd(&h[rows[e0 + k] >> 8], 1);
    __syncthreads();
    for (int j = t; j < nbu; j += 256) countsT[(size_t)blockIdx.x * nbu + j] = h[j];
}

// ---------- transpose counts [blk][b] -> [b][blk] (write-coalesced) ----------
__global__ void transpose_counts(const int* __restrict__ in, int* __restrict__ out,
                                 int nbk, int nbu) {
    int i = blockIdx.x * 256 + threadIdx.x;
    if (i < nbk * nbu) {
        int b = i / nbk, blk = i - b * nbk;
        out[i] = in[(size_t)blk * nbu + b];
    }
}

// ---------- flat exclusive scan: per-block pass ----------
#define SCAN_B 1024
__global__ void scanA_kernel(const int* __restrict__ in, int K,
                             int* __restrict__ excl, int* __restrict__ bsums) {
    __shared__ int sm[SCAN_B];
    int t = threadIdx.x;
    int g = blockIdx.x * SCAN_B + t;
    int v = (g < K) ? in[g] : 0;
    sm[t] = v;
    __syncthreads();
    for (int off = 1; off < SCAN_B; off <<= 1) {
        int u = (t >= off) ? sm[t - off] : 0;
        __syncthreads();
        sm[t] += u;
        __syncthreads();
    }
    if (g < K) excl[g] = sm[t] - v;
    if (t == SCAN_B - 1) bsums[blockIdx.x] = sm[t];
}

__global__ void scanB_kernel(int* __restrict__ bsums, int nb) {
    __shared__ int s[256];
    int t = threadIdx.x;
    int v = (t < nb) ? bsums[t] : 0;
    s[t] = v;
    __syncthreads();
    for (int off = 1; off < 256; off <<= 1) {
        int u = (t >= off) ? s[t - off] : 0;
        __syncthreads();
        s[t] += u;
        __syncthreads();
    }
    if (t < nb) bsums[t] = s[t] - v;
}

// ---------- Pass A2: LDS counting-sort block's edges by bucket, coalesced scatter ----------
__global__ __launch_bounds__(256) void a2_scatter(const int* __restrict__ rows,
                                                  const int* __restrict__ colsIn, int E,
                                                  const int* __restrict__ scanArr,
                                                  const int* __restrict__ bsums,
                                                  int nbk, int nbu,
                                                  int* __restrict__ packed) {
    __shared__ int cnt[NBU_PAD], start[NBU_PAD], cur[NBU_PAD];
    __shared__ int sortedV[EPB];
    __shared__ unsigned short sortedB[EPB];
    __shared__ int p[256];
    int t = threadIdx.x, blk = blockIdx.x;
    for (int i = t; i < NBU_PAD; i += 256) cnt[i] = 0;
    __syncthreads();
    int e0 = blk * EPB;
    int ecnt = min(EPB, E - e0);
    int myr[16], myc[16];
#pragma unroll
    for (int k = 0; k < 16; ++k) {
        int idx = k * 256 + t;
        if (idx < ecnt) {
            myr[k] = rows[e0 + idx];
            myc[k] = colsIn[e0 + idx];
            atomicAdd(&cnt[myr[k] >> 8], 1);
        }
    }
    __syncthreads();
    int a0 = cnt[2 * t], a1 = cnt[2 * t + 1];
    p[t] = a0 + a1;
    __syncthreads();
    for (int off = 1; off < 256; off <<= 1) {
        int u = (t >= off) ? p[t - off] : 0;
        __syncthreads();
        p[t] += u;
        __syncthreads();
    }
    int ex = p[t] - (a0 + a1);
    start[2 * t] = ex;      start[2 * t + 1] = ex + a0;
    cur[2 * t] = ex;        cur[2 * t + 1] = ex + a0;
    __syncthreads();
#pragma unroll
    for (int k = 0; k < 16; ++k) {
        int idx = k * 256 + t;
        if (idx < ecnt) {
            int b = myr[k] >> 8;
            int pos = atomicAdd(&cur[b], 1);
            sortedV[pos] = ((myr[k] & 255) << 17) | myc[k];
            sortedB[pos] = (unsigned short)b;
        }
    }
    __syncthreads();
    for (int j = t; j < nbu; j += 256) {
        int idx = j * nbk + blk;
        cnt[j] = scanArr[idx] + bsums[idx >> 10] - start[j];
    }
    __syncthreads();
    for (int i = t; i < ecnt; i += 256) {
        int b = sortedB[i];
        packed[cnt[b] + i] = sortedV[i];
    }
}

// ---------- Pass B: per-bucket LDS sort by row; emit colSort (BYTE offsets), row_ptr, inv ----------
__global__ __launch_bounds__(256) void b_sort(const int* __restrict__ packed,
                                              const int* __restrict__ scanArr,
                                              const int* __restrict__ bsums,
                                              int nbk, int nbu, int N, int E,
                                              int* __restrict__ colSort,
                                              int* __restrict__ row_ptr,
                                              float* __restrict__ inv) {
    __shared__ int cnt[RPB], start[RPB], cur[RPB], s[RPB];
    __shared__ int sv[BCAP];
    int t = threadIdx.x, b = blockIdx.x;
    int i0 = b * nbk;
    int base = scanArr[i0] + bsums[i0 >> 10];
    int nxt;
    if (b + 1 < nbu) {
        int i1 = (b + 1) * nbk;
        nxt = scanArr[i1] + bsums[i1 >> 10];
    } else nxt = E;
    int sz = nxt - base;
    cnt[t] = 0;
    __syncthreads();
    for (int i = t; i < sz; i += 256) atomicAdd(&cnt[(packed[base + i] >> 17) & 255], 1);
    __syncthreads();
    int c = cnt[t];
    s[t] = c;
    __syncthreads();
    for (int off = 1; off < 256; off <<= 1) {
        int u = (t >= off) ? s[t - off] : 0;
        __syncthreads();
        s[t] += u;
        __syncthreads();
    }
    start[t] = s[t] - c;
    cur[t] = s[t] - c;
    __syncthreads();
    for (int i = t; i < sz; i += 256) {
        int v = packed[base + i];
        int lr = (v >> 17) & 255;
        int pos = atomicAdd(&cur[lr], 1);
        if (pos < BCAP) sv[pos] = v & 0x1FFFF;
    }
    __syncthreads();
    // emit byte offsets (col * 256 bytes per bf16 row)
    for (int i = t; i < sz; i += 256) colSort[base + i] = sv[i] << 8;
    int r = b * RPB + t;
    if (r < N) {
        row_ptr[r] = base + start[t];
        inv[r] = rsqrtf((float)(c + 1));
    }
    if (b == 0 && t == 0) row_ptr[N] = E;
}

// ---------- bf16 helpers ----------
__device__ inline unsigned short f2bf(float x) {
    unsigned u = __float_as_uint(x);
    unsigned r = (u + 0x7FFFu + ((u >> 16) & 1u)) >> 16;   // RNE
    return (unsigned short)r;
}

__device__ inline void split2(float x0, float x1, unsigned& hw, unsigned& lw) {
    unsigned u0 = __float_as_uint(x0), u1 = __float_as_uint(x1);
    hw = (u1 & 0xFFFF0000u) | (u0 >> 16);
    float l0 = x0 - __uint_as_float(u0 & 0xFFFF0000u);   // exact
    float l1 = x1 - __uint_as_float(u1 & 0xFFFF0000u);   // exact
    lw = (__float_as_uint(l1) & 0xFFFF0000u) | (__float_as_uint(l0) >> 16);
}

// ---------- W prep: Wt_hi/Wt_lo[w][c][k] (bf16, transposed), all 3 layers in one launch ----------
__global__ void wsplit3_kernel(const float* __restrict__ W1, const float* __restrict__ W2,
                               const float* __restrict__ W3,
                               unsigned short* __restrict__ WtH,
                               unsigned short* __restrict__ WtL) {
    int w = blockIdx.y;
    const float* W = (w == 0) ? W1 : (w == 1) ? W2 : W3;
    int i = blockIdx.x * 256 + threadIdx.x;   // i = c*128 + k
    int c = i >> 7, k = i & 127;
    float wv = W[k * NFEAT + c];
    unsigned u = __float_as_uint(wv);
    unsigned hib = u & 0xFFFF0000u;
    float lo = wv - __uint_as_float(hib);
    WtH[w * NFEAT * NFEAT + i] = (unsigned short)(u >> 16);
    WtL[w * NFEAT * NFEAT + i] = (unsigned short)(__float_as_uint(lo) >> 16);
}

// ---------------- MFMA GEMM (f32 input, in-reg split): layer 1 ----------------
__global__ __launch_bounds__(256) void gemm_mfma_f32(const float* __restrict__ X,
                                                     const unsigned short* __restrict__ Wt_hi,
                                                     const unsigned short* __restrict__ Wt_lo,
                                                     const float* __restrict__ inv,
                                                     unsigned short* __restrict__ Hn, int n) {
    int tid = threadIdx.x;
    int wave = tid >> 6, lane = tid & 63;
    int lrow = lane & 15, kgrp = lane >> 4;
    int wcol0 = wave * 32;
    int rowbase = blockIdx.x * 64;

    bf16x8 bh[2][4], bl[2][4];
#pragma unroll
    for (int ct = 0; ct < 2; ++ct) {
        int col = wcol0 + ct * 16 + lrow;
        const unsigned short* ph = Wt_hi + (size_t)col * NFEAT + kgrp * 8;
        const unsigned short* pl = Wt_lo + (size_t)col * NFEAT + kgrp * 8;
#pragma unroll
        for (int ks = 0; ks < 4; ++ks) {
            bh[ct][ks] = *(const bf16x8*)(ph + ks * 32);
            bl[ct][ks] = *(const bf16x8*)(pl + ks * 32);
        }
    }

    union U8 { bf16x8 v; unsigned w[4]; };

#pragma unroll
    for (int rt = 0; rt < 4; ++rt) {
        int arow = rowbase + rt * 16 + lrow;
        int rc = arow < n ? arow : n - 1;
        const float* px = X + (size_t)rc * NFEAT + kgrp * 8;

        bf16x8 ah[4], al[4];
#pragma unroll
        for (int ks = 0; ks < 4; ++ks) {
            float4 v0 = *(const float4*)(px + ks * 32);
            float4 v1 = *(const float4*)(px + ks * 32 + 4);
            U8 uh, ul;
            split2(v0.x, v0.y, uh.w[0], ul.w[0]);
            split2(v0.z, v0.w, uh.w[1], ul.w[1]);
            split2(v1.x, v1.y, uh.w[2], ul.w[2]);
            split2(v1.z, v1.w, uh.w[3], ul.w[3]);
            ah[ks] = uh.v;
            al[ks] = ul.v;
        }

        f32x4 acc[2] = {{0.f, 0.f, 0.f, 0.f}, {0.f, 0.f, 0.f, 0.f}};
#pragma unroll
        for (int ks = 0; ks < 4; ++ks) {
#pragma unroll
            for (int ct = 0; ct < 2; ++ct) {
                acc[ct] = __builtin_amdgcn_mfma_f32_16x16x32_bf16(ah[ks], bh[ct][ks], acc[ct], 0, 0, 0);
                acc[ct] = __builtin_amdgcn_mfma_f32_16x16x32_bf16(ah[ks], bl[ct][ks], acc[ct], 0, 0, 0);
                acc[ct] = __builtin_amdgcn_mfma_f32_16x16x32_bf16(al[ks], bh[ct][ks], acc[ct], 0, 0, 0);
            }
        }

#pragma unroll
        for (int m = 0; m < 4; ++m) {
            int orow = rowbase + rt * 16 + kgrp * 4 + m;
            if (orow < n) {
                float sc = inv[orow];
#pragma unroll
                for (int ct = 0; ct < 2; ++ct) {
                    int col = wcol0 + ct * 16 + lrow;
                    Hn[(size_t)orow * NFEAT + col] = f2bf(acc[ct][m] * sc);
                }
            }
        }
    }
}

// ---------------- FUSED aggregate + GEMM (layer boundaries) ----------------
// Block = 1024 thr = 16 waves = 16 nodes. Phase 1: wave w aggregates node w
// (quarter-wave per edge, 4-deep). relu(agg*inv+b) rows parked in LDS
// (pad stride 132 -> 2-way banks). Phase 2: waves 0..7 each compute a 16-col
// tile of row*W_{l+1} (3-term bf16 split MFMA, B hoisted), write Hn_out*inv.
__global__ __launch_bounds__(1024) void agg_gemm(const unsigned short* __restrict__ HnIn,
                                                 const int* __restrict__ row_ptr,
                                                 const int* __restrict__ cols,  // byte offs
                                                 const float* __restrict__ inv,
                                                 const float* __restrict__ bias,
                                                 const unsigned short* __restrict__ WtHp,
                                                 const unsigned short* __restrict__ WtLp,
                                                 unsigned short* __restrict__ HnOut, int n) {
    __shared__ float Y[16][132];
    int tid = threadIdx.x;
    int wid = tid >> 6;
    int lane = tid & 63;
    int node = blockIdx.x * 16 + wid;
    int q = lane >> 4;
    unsigned fb = (lane & 15) << 4;
    const char* Hb = (const char*)HnIn;

    int lrow = lane & 15, kgrp = lane >> 4;

    // hoist B fragments (independent of aggregation) for MFMA waves
    bf16x8 bh[4], bl[4];
    if (wid < 8) {
        int col = wid * 16 + lrow;
        const unsigned short* ph = WtHp + (size_t)col * NFEAT + kgrp * 8;
        const unsigned short* pl = WtLp + (size_t)col * NFEAT + kgrp * 8;
#pragma unroll
        for (int ks = 0; ks < 4; ++ks) {
            bh[ks] = *(const bf16x8*)(ph + ks * 32);
            bl[ks] = *(const bf16x8*)(pl + ks * 32);
        }
    }

    float2 accA[4], accB[4];
#pragma unroll
    for (int k = 0; k < 4; ++k) {
        accA[k] = make_float2(0.f, 0.f);
        accB[k] = make_float2(0.f, 0.f);
    }

#define UNPK_ADD(ACC, W) do {                                              \
        unsigned _w = (W);                                                 \
        (ACC).x += __uint_as_float(_w << 16);                              \
        (ACC).y += __uint_as_float(_w & 0xFFFF0000u);                      \
    } while (0)

    if (node < n) {
        if (q == 0) {  // self loop term
            uint4 v = *(const uint4*)(Hb + ((unsigned)node << 8) + fb);
            const unsigned* u = (const unsigned*)&v;
#pragma unroll
            for (int k = 0; k < 4; ++k) UNPK_ADD(accA[k], u[k]);
        }
        int s = row_ptr[node], e = row_ptr[node + 1];
        int j = s + q;
        for (; j + 12 < e; j += 16) {
            unsigned o0 = (unsigned)cols[j];
            unsigned o1 = (unsigned)cols[j + 4];
            unsigned o2 = (unsigned)cols[j + 8];
            unsigned o3 = (unsigned)cols[j + 12];
            uint4 v0 = *(const uint4*)(Hb + o0 + fb);
            uint4 v1 = *(const uint4*)(Hb + o1 + fb);
            uint4 v2 = *(const uint4*)(Hb + o2 + fb);
            uint4 v3 = *(const uint4*)(Hb + o3 + fb);
            const unsigned* u0 = (const unsigned*)&v0;
            const unsigned* u1 = (const unsigned*)&v1;
            const unsigned* u2 = (const unsigned*)&v2;
            const unsigned* u3 = (const unsigned*)&v3;
#pragma unroll
            for (int k = 0; k < 4; ++k) {
                UNPK_ADD(accA[k], u0[k]);
                UNPK_ADD(accB[k], u1[k]);
                UNPK_ADD(accA[k], u2[k]);
                UNPK_ADD(accB[k], u3[k]);
            }
        }
        for (; j + 4 < e; j += 8) {
            unsigned o0 = (unsigned)cols[j];
            unsigned o1 = (unsigned)cols[j + 4];
            uint4 v0 = *(const uint4*)(Hb + o0 + fb);
            uint4 v1 = *(const uint4*)(Hb + o1 + fb);
            const unsigned* u0 = (const unsigned*)&v0;
            const unsigned* u1 = (const unsigned*)&v1;
#pragma unroll
            for (int k = 0; k < 4; ++k) {
                UNPK_ADD(accA[k], u0[k]);
                UNPK_ADD(accB[k], u1[k]);
            }
        }
        if (j < e) {
            unsigned o0 = (unsigned)cols[j];
            uint4 v0 = *(const uint4*)(Hb + o0 + fb);
            const unsigned* u0 = (const unsigned*)&v0;
#pragma unroll
            for (int k = 0; k < 4; ++k) UNPK_ADD(accA[k], u0[k]);
        }
    }
#undef UNPK_ADD

    float acc[8];
#pragma unroll
    for (int k = 0; k < 4; ++k) {
        acc[2 * k]     = accA[k].x + accB[k].x;
        acc[2 * k + 1] = accA[k].y + accB[k].y;
    }
#pragma unroll
    for (int k = 0; k < 8; ++k) {
        acc[k] += __shfl_xor(acc[k], 16, 64);
        acc[k] += __shfl_xor(acc[k], 32, 64);
    }

    if (q == 0) {
        float r[8];
        if (node < n) {
            unsigned f = (lane & 15) << 3;
            float inv_i = inv[node];
            float4 b0 = *(const float4*)(bias + f);
            float4 b1v = *(const float4*)(bias + f + 4);
            r[0] = fmaxf(acc[0] * inv_i + b0.x, 0.f);
            r[1] = fmaxf(acc[1] * inv_i + b0.y, 0.f);
            r[2] = fmaxf(acc[2] * inv_i + b0.z, 0.f);
            r[3] = fmaxf(acc[3] * inv_i + b0.w, 0.f);
            r[4] = fmaxf(acc[4] * inv_i + b1v.x, 0.f);
            r[5] = fmaxf(acc[5] * inv_i + b1v.y, 0.f);
            r[6] = fmaxf(acc[6] * inv_i + b1v.z, 0.f);
            r[7] = fmaxf(acc[7] * inv_i + b1v.w, 0.f);
        } else {
#pragma unroll
            for (int k = 0; k < 8; ++k) r[k] = 0.f;
        }
        int c0 = (lane & 15) * 8;
        *(float4*)&Y[wid][c0]     = make_float4(r[0], r[1], r[2], r[3]);
        *(float4*)&Y[wid][c0 + 4] = make_float4(r[4], r[5], r[6], r[7]);
    }
    __syncthreads();
    if (wid >= 8) return;

    // Phase 2: wave wid owns col-tile ct=wid
    union U8 { bf16x8 v; unsigned w[4]; };
    bf16x8 ah[4], al[4];
#pragma unroll
    for (int ks = 0; ks < 4; ++ks) {
        const float* py = &Y[lrow][kgrp * 8 + ks * 32];
        float4 v0 = *(const float4*)py;
        float4 v1 = *(const float4*)(py + 4);
        U8 uh, ul;
        split2(v0.x, v0.y, uh.w[0], ul.w[0]);
        split2(v0.z, v0.w, uh.w[1], ul.w[1]);
        split2(v1.x, v1.y, uh.w[2], ul.w[2]);
        split2(v1.z, v1.w, uh.w[3], ul.w[3]);
        ah[ks] = uh.v;
        al[ks] = ul.v;
    }

    f32x4 acc2 = {0.f, 0.f, 0.f, 0.f};
#pragma unroll
    for (int ks = 0; ks < 4; ++ks) {
        acc2 = __builtin_amdgcn_mfma_f32_16x16x32_bf16(ah[ks], bh[ks], acc2, 0, 0, 0);
        acc2 = __builtin_amdgcn_mfma_f32_16x16x32_bf16(ah[ks], bl[ks], acc2, 0, 0, 0);
        acc2 = __builtin_amdgcn_mfma_f32_16x16x32_bf16(al[ks], bh[ks], acc2, 0, 0, 0);
    }

    int nb0 = blockIdx.x * 16;
    int col = wid * 16 + lrow;
#pragma unroll
    for (int m = 0; m < 4; ++m) {
        int orow = nb0 + kgrp * 4 + m;
        if (orow < n) {
            HnOut[(size_t)orow * NFEAT + col] = f2bf(acc2[m] * inv[orow]);
        }
    }
}

// ---------------- Final aggregation (layer 3): f32 out ----------------
__global__ __launch_bounds__(256) void aggregate_final(const unsigned short* __restrict__ Hn,
                                                       const int* __restrict__ row_ptr,
                                                       const int* __restrict__ cols,
                                                       const float* __restrict__ inv,
                                                       const float* __restrict__ bias,
                                                       float* __restrict__ out, int n) {
    int node = blockIdx.x * (blockDim.x >> 6) + (threadIdx.x >> 6);
    if (node >= n) return;
    int lane = threadIdx.x & 63;
    int q = lane >> 4;
    unsigned fb = (lane & 15) << 4;
    const char* Hb = (const char*)Hn;

    float2 accA[4], accB[4];
#pragma unroll
    for (int k = 0; k < 4; ++k) {
        accA[k] = make_float2(0.f, 0.f);
        accB[k] = make_float2(0.f, 0.f);
    }

#define UNPK_ADD(ACC, W) do {                                              \
        unsigned _w = (W);                                                 \
        (ACC).x += __uint_as_float(_w << 16);                              \
        (ACC).y += __uint_as_float(_w & 0xFFFF0000u);                      \
    } while (0)

    if (q == 0) {
        uint4 v = *(const uint4*)(Hb + ((unsigned)node << 8) + fb);
        const unsigned* u = (const unsigned*)&v;
#pragma unroll
        for (int k = 0; k < 4; ++k) UNPK_ADD(accA[k], u[k]);
    }
    int s = row_ptr[node], e = row_ptr[node + 1];
    int j = s + q;
    for (; j + 12 < e; j += 16) {
        unsigned o0 = (unsigned)cols[j];
        unsigned o1 = (unsigned)cols[j + 4];
        unsigned o2 = (unsigned)cols[j + 8];
        unsigned o3 = (unsigned)cols[j + 12];
        uint4 v0 = *(const uint4*)(Hb + o0 + fb);
        uint4 v1 = *(const uint4*)(Hb + o1 + fb);
        uint4 v2 = *(const uint4*)(Hb + o2 + fb);
        uint4 v3 = *(const uint4*)(Hb + o3 + fb);
        const unsigned* u0 = (const unsigned*)&v0;
        const unsigned* u1 = (const unsigned*)&v1;
        const unsigned* u2 = (const unsigned*)&v2;
        const unsigned* u3 = (const unsigned*)&v3;
#pragma unroll
        for (int k = 0; k < 4; ++k) {
            UNPK_ADD(accA[k], u0[k]);
            UNPK_ADD(accB[k], u1[k]);
            UNPK_ADD(accA[k], u2[k]);
            UNPK_ADD(accB[k], u3[k]);
        }
    }
    for (; j + 4 < e; j += 8) {
        unsigned o0 = (unsigned)cols[j];
        unsigned o1 = (unsigned)cols[j + 4];
        uint4 v0 = *(const uint4*)(Hb + o0 + fb);
        uint4 v1 = *(const uint4*)(Hb + o1 + fb);
        const unsigned* u0 = (const unsigned*)&v0;
        const unsigned* u1 = (const unsigned*)&v1;
#pragma unroll
        for (int k = 0; k < 4; ++k) {
            UNPK_ADD(accA[k], u0[k]);
            UNPK_ADD(accB[k], u1[k]);
        }
    }
    if (j < e) {
        unsigned o0 = (unsigned)cols[j];
        uint4 v0 = *(const uint4*)(Hb + o0 + fb);
        const unsigned* u0 = (const unsigned*)&v0;
#pragma unroll
        for (int k = 0; k < 4; ++k) UNPK_ADD(accA[k], u0[k]);
    }
#undef UNPK_ADD

    float acc[8];
#pragma unroll
    for (int k = 0; k < 4; ++k) {
        acc[2 * k]     = accA[k].x + accB[k].x;
        acc[2 * k + 1] = accA[k].y + accB[k].y;
    }
#pragma unroll
    for (int k = 0; k < 8; ++k) {
        acc[k] += __shfl_xor(acc[k], 16, 64);
        acc[k] += __shfl_xor(acc[k], 32, 64);
    }

    if (q == 0) {
        unsigned f = (lane & 15) << 3;
        float inv_i = inv[node];
        float4 b0 = *(const float4*)(bias + f);
        float4 b1v = *(const float4*)(bias + f + 4);
        *(float4*)(out + (size_t)node * NFEAT + f) =
            make_float4(acc[0] * inv_i + b0.x, acc[1] * inv_i + b0.y,
                        acc[2] * inv_i + b0.z, acc[3] * inv_i + b0.w);
        *(float4*)(out + (size_t)node * NFEAT + f + 4) =
            make_float4(acc[4] * inv_i + b1v.x, acc[5] * inv_i + b1v.y,
                        acc[6] * inv_i + b1v.z, acc[7] * inv_i + b1v.w);
    }
}

// ---------------- launch ----------------
static inline size_t align256(size_t x) { return (x + 255) & ~(size_t)255; }

extern "C" void kernel_launch(void* const* d_in, const int* in_sizes, int n_in,
                              void* d_out, int out_size, void* d_ws, size_t ws_size,
                              hipStream_t stream) {
    const float* x   = (const float*)d_in[0];
    const int*   ei  = (const int*)d_in[1];
    const float* W1  = (const float*)d_in[2];
    const float* b1  = (const float*)d_in[3];
    const float* W2  = (const float*)d_in[4];
    const float* b2  = (const float*)d_in[5];
    const float* W3  = (const float*)d_in[6];
    const float* b3  = (const float*)d_in[7];
    float* out = (float*)d_out;

    const int N = in_sizes[0] / NFEAT;
    const int E = in_sizes[1] / 2;
    const int* rows = ei;
    const int* colsIn = ei + E;

    const int nbk = (E + EPB - 1) / EPB;       // edge blocks
    const int nbu = (N + RPB - 1) / RPB;       // row buckets
    const int K = nbk * nbu;

    // workspace layout
    char* ws = (char*)d_ws;
    size_t off = 0;
    unsigned short* Hn = (unsigned short*)(ws + off);
    off = align256(off + (size_t)N * NFEAT * sizeof(unsigned short));
    unsigned short* Hn2 = (unsigned short*)(ws + off);
    off = align256(off + (size_t)N * NFEAT * sizeof(unsigned short));
    int*   bufA    = (int*)(ws + off);   off = align256(off + (size_t)K * sizeof(int));
    int*   bufB    = (int*)(ws + off);   off = align256(off + (size_t)K * sizeof(int));
    int*   bsums   = (int*)(ws + off);   off = align256(off + (size_t)256 * sizeof(int));
    int*   packed  = (int*)(ws + off);   off = align256(off + (size_t)E * sizeof(int));
    int*   colSort = (int*)(ws + off);   off = align256(off + (size_t)E * sizeof(int));
    int*   row_ptr = (int*)(ws + off);   off = align256(off + (size_t)(N + 1) * sizeof(int));
    float* inv     = (float*)(ws + off); off = align256(off + (size_t)N * sizeof(float));
    unsigned short* WtH = (unsigned short*)(ws + off);
    off = align256(off + (size_t)3 * NFEAT * NFEAT * sizeof(unsigned short));
    unsigned short* WtL = (unsigned short*)(ws + off);
    off = align256(off + (size_t)3 * NFEAT * NFEAT * sizeof(unsigned short));
    (void)ws_size; (void)n_in; (void)out_size;

    const int nb2 = (K + SCAN_B - 1) / SCAN_B;

    // --- W splits (one launch for all 3 layers) ---
    wsplit3_kernel<<<dim3(64, 3), 256, 0, stream>>>(W1, W2, W3, WtH, WtL);

    // --- CSR build (coalesced counting sort) ---
    a1_hist<<<nbk, 256, 0, stream>>>(rows, E, bufA, nbu);
    transpose_counts<<<(K + 255) / 256, 256, 0, stream>>>(bufA, bufB, nbk, nbu);
    scanA_kernel<<<nb2, SCAN_B, 0, stream>>>(bufB, K, bufA, bsums);
    scanB_kernel<<<1, 256, 0, stream>>>(bsums, nb2);
    a2_scatter<<<nbk, 256, 0, stream>>>(rows, colsIn, E, bufA, bsums, nbk, nbu, packed);
    b_sort<<<nbu, 256, 0, stream>>>(packed, bufA, bsums, nbk, nbu, N, E, colSort, row_ptr, inv);

    const int gemm_grid = (N + 63) / 64;
    const int fuse_grid = (N + 15) / 16;
    const int agg_grid  = (N + 3) / 4;

    // --- layer 1 GEMM ---
    gemm_mfma_f32<<<gemm_grid, 256, 0, stream>>>(x, WtH, WtL, inv, Hn, N);
    // --- agg(L1) + GEMM(L2) fused ---
    agg_gemm<<<fuse_grid, 1024, 0, stream>>>(Hn, row_ptr, colSort, inv, b1,
                                             WtH + NFEAT * NFEAT, WtL + NFEAT * NFEAT, Hn2, N);
    // --- agg(L2) + GEMM(L3) fused ---
    agg_gemm<<<fuse_grid, 1024, 0, stream>>>(Hn2, row_ptr, colSort, inv, b2,
                                             WtH + 2 * NFEAT * NFEAT, WtL + 2 * NFEAT * NFEAT, Hn, N);
    // --- final aggregation ---
    aggregate_final<<<agg_grid, 256, 0, stream>>>(Hn, row_ptr, colSort, inv, b3, out, N);
}

// Round 8
// 460.312 us; speedup vs baseline: 1.0559x; 1.0559x over previous
//
#include <hip/hip_runtime.h>
#include <hip/hip_bf16.h>

#define NFEAT 128
#define EPB   4096          // edges per A-block (16 per thread * 256)
#define RPB   256           // rows per bucket (bucket = row >> 8)
#define NBU_PAD 512
#define BCAP  6144          // bucket capacity in pass B (mean ~4092, +32 sigma)

typedef short bf16x8 __attribute__((ext_vector_type(8)));
typedef float f32x4  __attribute__((ext_vector_type(4)));

// ---------- Pass A1: per-block bucket histogram (LDS), coalesced write ----------
__global__ __launch_bounds__(256) void a1_hist(const int* __restrict__ rows, int E,
                                               int* __restrict__ countsT, int nbu) {
    __shared__ int h[NBU_PAD];
    int t = threadIdx.x;
    for (int i = t; i < NBU_PAD; i += 256) h[i] = 0;
    __syncthreads();
    int e0 = blockIdx.x * EPB;
    int ecnt = min(EPB, E - e0);
    for (int k = t; k < ecnt; k += 256) atomicAdd(&h[rows[e0 + k] >> 8], 1);
    __syncthreads();
    for (int j = t; j < nbu; j += 256) countsT[(size_t)blockIdx.x * nbu + j] = h[j];
}

// ---------- transpose counts [blk][b] -> [b][blk] (write-coalesced) ----------
__global__ void transpose_counts(const int* __restrict__ in, int* __restrict__ out,
                                 int nbk, int nbu) {
    int i = blockIdx.x * 256 + threadIdx.x;
    if (i < nbk * nbu) {
        int b = i / nbk, blk = i - b * nbk;
        out[i] = in[(size_t)blk * nbu + b];
    }
}

// ---------- flat exclusive scan: per-block pass ----------
#define SCAN_B 1024
__global__ void scanA_kernel(const int* __restrict__ in, int K,
                             int* __restrict__ excl, int* __restrict__ bsums) {
    __shared__ int sm[SCAN_B];
    int t = threadIdx.x;
    int g = blockIdx.x * SCAN_B + t;
    int v = (g < K) ? in[g] : 0;
    sm[t] = v;
    __syncthreads();
    for (int off = 1; off < SCAN_B; off <<= 1) {
        int u = (t >= off) ? sm[t - off] : 0;
        __syncthreads();
        sm[t] += u;
        __syncthreads();
    }
    if (g < K) excl[g] = sm[t] - v;
    if (t == SCAN_B - 1) bsums[blockIdx.x] = sm[t];
}

__global__ void scanB_kernel(int* __restrict__ bsums, int nb) {
    __shared__ int s[256];
    int t = threadIdx.x;
    int v = (t < nb) ? bsums[t] : 0;
    s[t] = v;
    __syncthreads();
    for (int off = 1; off < 256; off <<= 1) {
        int u = (t >= off) ? s[t - off] : 0;
        __syncthreads();
        s[t] += u;
        __syncthreads();
    }
    if (t < nb) bsums[t] = s[t] - v;
}

// ---------- Pass A2: LDS counting-sort block's edges by bucket, coalesced scatter ----------
__global__ __launch_bounds__(256) void a2_scatter(const int* __restrict__ rows,
                                                  const int* __restrict__ colsIn, int E,
                                                  const int* __restrict__ scanArr,
                                                  const int* __restrict__ bsums,
                                                  int nbk, int nbu,
                                                  int* __restrict__ packed) {
    __shared__ int cnt[NBU_PAD], start[NBU_PAD], cur[NBU_PAD];
    __shared__ int sortedV[EPB];
    __shared__ unsigned short sortedB[EPB];
    __shared__ int p[256];
    int t = threadIdx.x, blk = blockIdx.x;
    for (int i = t; i < NBU_PAD; i += 256) cnt[i] = 0;
    __syncthreads();
    int e0 = blk * EPB;
    int ecnt = min(EPB, E - e0);
    int myr[16], myc[16];
#pragma unroll
    for (int k = 0; k < 16; ++k) {
        int idx = k * 256 + t;
        if (idx < ecnt) {
            myr[k] = rows[e0 + idx];
            myc[k] = colsIn[e0 + idx];
            atomicAdd(&cnt[myr[k] >> 8], 1);
        }
    }
    __syncthreads();
    int a0 = cnt[2 * t], a1 = cnt[2 * t + 1];
    p[t] = a0 + a1;
    __syncthreads();
    for (int off = 1; off < 256; off <<= 1) {
        int u = (t >= off) ? p[t - off] : 0;
        __syncthreads();
        p[t] += u;
        __syncthreads();
    }
    int ex = p[t] - (a0 + a1);
    start[2 * t] = ex;      start[2 * t + 1] = ex + a0;
    cur[2 * t] = ex;        cur[2 * t + 1] = ex + a0;
    __syncthreads();
#pragma unroll
    for (int k = 0; k < 16; ++k) {
        int idx = k * 256 + t;
        if (idx < ecnt) {
            int b = myr[k] >> 8;
            int pos = atomicAdd(&cur[b], 1);
            sortedV[pos] = ((myr[k] & 255) << 17) | myc[k];
            sortedB[pos] = (unsigned short)b;
        }
    }
    __syncthreads();
    for (int j = t; j < nbu; j += 256) {
        int idx = j * nbk + blk;
        cnt[j] = scanArr[idx] + bsums[idx >> 10] - start[j];
    }
    __syncthreads();
    for (int i = t; i < ecnt; i += 256) {
        int b = sortedB[i];
        packed[cnt[b] + i] = sortedV[i];
    }
}

// ---------- Pass B: per-bucket LDS sort by row; emit colSort (BYTE offsets), row_ptr, inv ----------
__global__ __launch_bounds__(256) void b_sort(const int* __restrict__ packed,
                                              const int* __restrict__ scanArr,
                                              const int* __restrict__ bsums,
                                              int nbk, int nbu, int N, int E,
                                              int* __restrict__ colSort,
                                              int* __restrict__ row_ptr,
                                              float* __restrict__ inv) {
    __shared__ int cnt[RPB], start[RPB], cur[RPB], s[RPB];
    __shared__ int sv[BCAP];
    int t = threadIdx.x, b = blockIdx.x;
    int i0 = b * nbk;
    int base = scanArr[i0] + bsums[i0 >> 10];
    int nxt;
    if (b + 1 < nbu) {
        int i1 = (b + 1) * nbk;
        nxt = scanArr[i1] + bsums[i1 >> 10];
    } else nxt = E;
    int sz = nxt - base;
    cnt[t] = 0;
    __syncthreads();
    for (int i = t; i < sz; i += 256) atomicAdd(&cnt[(packed[base + i] >> 17) & 255], 1);
    __syncthreads();
    int c = cnt[t];
    s[t] = c;
    __syncthreads();
    for (int off = 1; off < 256; off <<= 1) {
        int u = (t >= off) ? s[t - off] : 0;
        __syncthreads();
        s[t] += u;
        __syncthreads();
    }
    start[t] = s[t] - c;
    cur[t] = s[t] - c;
    __syncthreads();
    for (int i = t; i < sz; i += 256) {
        int v = packed[base + i];
        int lr = (v >> 17) & 255;
        int pos = atomicAdd(&cur[lr], 1);
        if (pos < BCAP) sv[pos] = v & 0x1FFFF;
    }
    __syncthreads();
    // emit byte offsets (col * 256 bytes per bf16 row)
    for (int i = t; i < sz; i += 256) colSort[base + i] = sv[i] << 8;
    int r = b * RPB + t;
    if (r < N) {
        row_ptr[r] = base + start[t];
        inv[r] = rsqrtf((float)(c + 1));
    }
    if (b == 0 && t == 0) row_ptr[N] = E;
}

// ---------- bf16 helpers ----------
__device__ inline unsigned short f2bf(float x) {
    unsigned u = __float_as_uint(x);
    unsigned r = (u + 0x7FFFu + ((u >> 16) & 1u)) >> 16;   // RNE
    return (unsigned short)r;
}

__device__ inline void split2(float x0, float x1, unsigned& hw, unsigned& lw) {
    unsigned u0 = __float_as_uint(x0), u1 = __float_as_uint(x1);
    hw = (u1 & 0xFFFF0000u) | (u0 >> 16);
    float l0 = x0 - __uint_as_float(u0 & 0xFFFF0000u);   // exact
    float l1 = x1 - __uint_as_float(u1 & 0xFFFF0000u);   // exact
    lw = (__float_as_uint(l1) & 0xFFFF0000u) | (__float_as_uint(l0) >> 16);
}

// ---------- W prep: Wt_hi/Wt_lo[w][c][k] (bf16, transposed), all 3 layers in one launch ----------
__global__ void wsplit3_kernel(const float* __restrict__ W1, const float* __restrict__ W2,
                               const float* __restrict__ W3,
                               unsigned short* __restrict__ WtH,
                               unsigned short* __restrict__ WtL) {
    int w = blockIdx.y;
    const float* W = (w == 0) ? W1 : (w == 1) ? W2 : W3;
    int i = blockIdx.x * 256 + threadIdx.x;   // i = c*128 + k
    int c = i >> 7, k = i & 127;
    float wv = W[k * NFEAT + c];
    unsigned u = __float_as_uint(wv);
    unsigned hib = u & 0xFFFF0000u;
    float lo = wv - __uint_as_float(hib);
    WtH[w * NFEAT * NFEAT + i] = (unsigned short)(u >> 16);
    WtL[w * NFEAT * NFEAT + i] = (unsigned short)(__float_as_uint(lo) >> 16);
}

// ---------------- MFMA GEMM (f32 input, in-reg split): layer 1 ----------------
__global__ __launch_bounds__(256) void gemm_mfma_f32(const float* __restrict__ X,
                                                     const unsigned short* __restrict__ Wt_hi,
                                                     const unsigned short* __restrict__ Wt_lo,
                                                     const float* __restrict__ inv,
                                                     unsigned short* __restrict__ Hn, int n) {
    int tid = threadIdx.x;
    int wave = tid >> 6, lane = tid & 63;
    int lrow = lane & 15, kgrp = lane >> 4;
    int wcol0 = wave * 32;
    int rowbase = blockIdx.x * 64;

    bf16x8 bh[2][4], bl[2][4];
#pragma unroll
    for (int ct = 0; ct < 2; ++ct) {
        int col = wcol0 + ct * 16 + lrow;
        const unsigned short* ph = Wt_hi + (size_t)col * NFEAT + kgrp * 8;
        const unsigned short* pl = Wt_lo + (size_t)col * NFEAT + kgrp * 8;
#pragma unroll
        for (int ks = 0; ks < 4; ++ks) {
            bh[ct][ks] = *(const bf16x8*)(ph + ks * 32);
            bl[ct][ks] = *(const bf16x8*)(pl + ks * 32);
        }
    }

    union U8 { bf16x8 v; unsigned w[4]; };

#pragma unroll
    for (int rt = 0; rt < 4; ++rt) {
        int arow = rowbase + rt * 16 + lrow;
        int rc = arow < n ? arow : n - 1;
        const float* px = X + (size_t)rc * NFEAT + kgrp * 8;

        bf16x8 ah[4], al[4];
#pragma unroll
        for (int ks = 0; ks < 4; ++ks) {
            float4 v0 = *(const float4*)(px + ks * 32);
            float4 v1 = *(const float4*)(px + ks * 32 + 4);
            U8 uh, ul;
            split2(v0.x, v0.y, uh.w[0], ul.w[0]);
            split2(v0.z, v0.w, uh.w[1], ul.w[1]);
            split2(v1.x, v1.y, uh.w[2], ul.w[2]);
            split2(v1.z, v1.w, uh.w[3], ul.w[3]);
            ah[ks] = uh.v;
            al[ks] = ul.v;
        }

        f32x4 acc[2] = {{0.f, 0.f, 0.f, 0.f}, {0.f, 0.f, 0.f, 0.f}};
#pragma unroll
        for (int ks = 0; ks < 4; ++ks) {
#pragma unroll
            for (int ct = 0; ct < 2; ++ct) {
                acc[ct] = __builtin_amdgcn_mfma_f32_16x16x32_bf16(ah[ks], bh[ct][ks], acc[ct], 0, 0, 0);
                acc[ct] = __builtin_amdgcn_mfma_f32_16x16x32_bf16(ah[ks], bl[ct][ks], acc[ct], 0, 0, 0);
                acc[ct] = __builtin_amdgcn_mfma_f32_16x16x32_bf16(al[ks], bh[ct][ks], acc[ct], 0, 0, 0);
            }
        }

#pragma unroll
        for (int m = 0; m < 4; ++m) {
            int orow = rowbase + rt * 16 + kgrp * 4 + m;
            if (orow < n) {
                float sc = inv[orow];
#pragma unroll
                for (int ct = 0; ct < 2; ++ct) {
                    int col = wcol0 + ct * 16 + lrow;
                    Hn[(size_t)orow * NFEAT + col] = f2bf(acc[ct][m] * sc);
                }
            }
        }
    }
}

// ---------------- FUSED aggregate + GEMM (layer boundaries), aggregation-shaped ----------------
// Block = 256 thr = 4 waves, 16 nodes/block. Each wave aggregates 4 nodes
// sequentially (quarter-wave/edge, 4-deep — same shape as the pure aggregate
// kernel), parks relu(agg*inv+b) rows in LDS Y[16][132]. One 4-wave barrier.
// Then ALL 4 waves each compute two 16-col MFMA tiles of Y@W (B loaded after
// the barrier from L2-hot W; 3-term bf16 split), write HnOut*inv.
__global__ __launch_bounds__(256) void agg_gemm(const unsigned short* __restrict__ HnIn,
                                                const int* __restrict__ row_ptr,
                                                const int* __restrict__ cols,  // byte offs
                                                const float* __restrict__ inv,
                                                const float* __restrict__ bias,
                                                const unsigned short* __restrict__ WtHp,
                                                const unsigned short* __restrict__ WtLp,
                                                unsigned short* __restrict__ HnOut, int n) {
    __shared__ float Y[16][132];
    int tid = threadIdx.x;
    int wid = tid >> 6;
    int lane = tid & 63;
    int q = lane >> 4;
    unsigned fb = (lane & 15) << 4;
    const char* Hb = (const char*)HnIn;
    int nb0 = blockIdx.x * 16;

#define UNPK_ADD(ACC, W) do {                                              \
        unsigned _w = (W);                                                 \
        (ACC).x += __uint_as_float(_w << 16);                              \
        (ACC).y += __uint_as_float(_w & 0xFFFF0000u);                      \
    } while (0)

    // ---- Phase 1: each wave aggregates 4 nodes sequentially ----
    for (int sub = 0; sub < 4; ++sub) {
        int rl = sub * 4 + wid;        // local row 0..15
        int node = nb0 + rl;

        float2 accA[4], accB[4];
#pragma unroll
        for (int k = 0; k < 4; ++k) {
            accA[k] = make_float2(0.f, 0.f);
            accB[k] = make_float2(0.f, 0.f);
        }

        if (node < n) {
            if (q == 0) {  // self loop term
                uint4 v = *(const uint4*)(Hb + ((unsigned)node << 8) + fb);
                const unsigned* u = (const unsigned*)&v;
#pragma unroll
                for (int k = 0; k < 4; ++k) UNPK_ADD(accA[k], u[k]);
            }
            int s = row_ptr[node], e = row_ptr[node + 1];
            int j = s + q;
            for (; j + 12 < e; j += 16) {
                unsigned o0 = (unsigned)cols[j];
                unsigned o1 = (unsigned)cols[j + 4];
                unsigned o2 = (unsigned)cols[j + 8];
                unsigned o3 = (unsigned)cols[j + 12];
                uint4 v0 = *(const uint4*)(Hb + o0 + fb);
                uint4 v1 = *(const uint4*)(Hb + o1 + fb);
                uint4 v2 = *(const uint4*)(Hb + o2 + fb);
                uint4 v3 = *(const uint4*)(Hb + o3 + fb);
                const unsigned* u0 = (const unsigned*)&v0;
                const unsigned* u1 = (const unsigned*)&v1;
                const unsigned* u2 = (const unsigned*)&v2;
                const unsigned* u3 = (const unsigned*)&v3;
#pragma unroll
                for (int k = 0; k < 4; ++k) {
                    UNPK_ADD(accA[k], u0[k]);
                    UNPK_ADD(accB[k], u1[k]);
                    UNPK_ADD(accA[k], u2[k]);
                    UNPK_ADD(accB[k], u3[k]);
                }
            }
            for (; j + 4 < e; j += 8) {
                unsigned o0 = (unsigned)cols[j];
                unsigned o1 = (unsigned)cols[j + 4];
                uint4 v0 = *(const uint4*)(Hb + o0 + fb);
                uint4 v1 = *(const uint4*)(Hb + o1 + fb);
                const unsigned* u0 = (const unsigned*)&v0;
                const unsigned* u1 = (const unsigned*)&v1;
#pragma unroll
                for (int k = 0; k < 4; ++k) {
                    UNPK_ADD(accA[k], u0[k]);
                    UNPK_ADD(accB[k], u1[k]);
                }
            }
            if (j < e) {
                unsigned o0 = (unsigned)cols[j];
                uint4 v0 = *(const uint4*)(Hb + o0 + fb);
                const unsigned* u0 = (const unsigned*)&v0;
#pragma unroll
                for (int k = 0; k < 4; ++k) UNPK_ADD(accA[k], u0[k]);
            }
        }

        float acc[8];
#pragma unroll
        for (int k = 0; k < 4; ++k) {
            acc[2 * k]     = accA[k].x + accB[k].x;
            acc[2 * k + 1] = accA[k].y + accB[k].y;
        }
#pragma unroll
        for (int k = 0; k < 8; ++k) {
            acc[k] += __shfl_xor(acc[k], 16, 64);
            acc[k] += __shfl_xor(acc[k], 32, 64);
        }

        if (q == 0) {
            float r[8];
            if (node < n) {
                unsigned f = (lane & 15) << 3;
                float inv_i = inv[node];
                float4 b0 = *(const float4*)(bias + f);
                float4 b1v = *(const float4*)(bias + f + 4);
                r[0] = fmaxf(acc[0] * inv_i + b0.x, 0.f);
                r[1] = fmaxf(acc[1] * inv_i + b0.y, 0.f);
                r[2] = fmaxf(acc[2] * inv_i + b0.z, 0.f);
                r[3] = fmaxf(acc[3] * inv_i + b0.w, 0.f);
                r[4] = fmaxf(acc[4] * inv_i + b1v.x, 0.f);
                r[5] = fmaxf(acc[5] * inv_i + b1v.y, 0.f);
                r[6] = fmaxf(acc[6] * inv_i + b1v.z, 0.f);
                r[7] = fmaxf(acc[7] * inv_i + b1v.w, 0.f);
            } else {
#pragma unroll
                for (int k = 0; k < 8; ++k) r[k] = 0.f;
            }
            int c0 = (lane & 15) * 8;
            *(float4*)&Y[rl][c0]     = make_float4(r[0], r[1], r[2], r[3]);
            *(float4*)&Y[rl][c0 + 4] = make_float4(r[4], r[5], r[6], r[7]);
        }
    }
#undef UNPK_ADD
    __syncthreads();

    // ---- Phase 2: all 4 waves; wave wid owns col-tiles 2*wid, 2*wid+1 ----
    int lrow = lane & 15, kgrp = lane >> 4;
    union U8 { bf16x8 v; unsigned w[4]; };
    bf16x8 ah[4], al[4];
#pragma unroll
    for (int ks = 0; ks < 4; ++ks) {
        const float* py = &Y[lrow][kgrp * 8 + ks * 32];
        float4 v0 = *(const float4*)py;
        float4 v1 = *(const float4*)(py + 4);
        U8 uh, ul;
        split2(v0.x, v0.y, uh.w[0], ul.w[0]);
        split2(v0.z, v0.w, uh.w[1], ul.w[1]);
        split2(v1.x, v1.y, uh.w[2], ul.w[2]);
        split2(v1.z, v1.w, uh.w[3], ul.w[3]);
        ah[ks] = uh.v;
        al[ks] = ul.v;
    }

    float invc[4];
#pragma unroll
    for (int m = 0; m < 4; ++m) {
        int orow = nb0 + kgrp * 4 + m;
        invc[m] = (orow < n) ? inv[orow] : 0.f;
    }

#pragma unroll
    for (int ct = 0; ct < 2; ++ct) {
        int col = (wid * 2 + ct) * 16 + lrow;
        const unsigned short* ph = WtHp + (size_t)col * NFEAT + kgrp * 8;
        const unsigned short* pl = WtLp + (size_t)col * NFEAT + kgrp * 8;
        bf16x8 bh[4], bl[4];
#pragma unroll
        for (int ks = 0; ks < 4; ++ks) {
            bh[ks] = *(const bf16x8*)(ph + ks * 32);
            bl[ks] = *(const bf16x8*)(pl + ks * 32);
        }
        f32x4 acc2 = {0.f, 0.f, 0.f, 0.f};
#pragma unroll
        for (int ks = 0; ks < 4; ++ks) {
            acc2 = __builtin_amdgcn_mfma_f32_16x16x32_bf16(ah[ks], bh[ks], acc2, 0, 0, 0);
            acc2 = __builtin_amdgcn_mfma_f32_16x16x32_bf16(ah[ks], bl[ks], acc2, 0, 0, 0);
            acc2 = __builtin_amdgcn_mfma_f32_16x16x32_bf16(al[ks], bh[ks], acc2, 0, 0, 0);
        }
#pragma unroll
        for (int m = 0; m < 4; ++m) {
            int orow = nb0 + kgrp * 4 + m;
            if (orow < n) {
                HnOut[(size_t)orow * NFEAT + col] = f2bf(acc2[m] * invc[m]);
            }
        }
    }
}

// ---------------- Final aggregation (layer 3): f32 out ----------------
__global__ __launch_bounds__(256) void aggregate_final(const unsigned short* __restrict__ Hn,
                                                       const int* __restrict__ row_ptr,
                                                       const int* __restrict__ cols,
                                                       const float* __restrict__ inv,
                                                       const float* __restrict__ bias,
                                                       float* __restrict__ out, int n) {
    int node = blockIdx.x * (blockDim.x >> 6) + (threadIdx.x >> 6);
    if (node >= n) return;
    int lane = threadIdx.x & 63;
    int q = lane >> 4;
    unsigned fb = (lane & 15) << 4;
    const char* Hb = (const char*)Hn;

    float2 accA[4], accB[4];
#pragma unroll
    for (int k = 0; k < 4; ++k) {
        accA[k] = make_float2(0.f, 0.f);
        accB[k] = make_float2(0.f, 0.f);
    }

#define UNPK_ADD(ACC, W) do {                                              \
        unsigned _w = (W);                                                 \
        (ACC).x += __uint_as_float(_w << 16);                              \
        (ACC).y += __uint_as_float(_w & 0xFFFF0000u);                      \
    } while (0)

    if (q == 0) {
        uint4 v = *(const uint4*)(Hb + ((unsigned)node << 8) + fb);
        const unsigned* u = (const unsigned*)&v;
#pragma unroll
        for (int k = 0; k < 4; ++k) UNPK_ADD(accA[k], u[k]);
    }
    int s = row_ptr[node], e = row_ptr[node + 1];
    int j = s + q;
    for (; j + 12 < e; j += 16) {
        unsigned o0 = (unsigned)cols[j];
        unsigned o1 = (unsigned)cols[j + 4];
        unsigned o2 = (unsigned)cols[j + 8];
        unsigned o3 = (unsigned)cols[j + 12];
        uint4 v0 = *(const uint4*)(Hb + o0 + fb);
        uint4 v1 = *(const uint4*)(Hb + o1 + fb);
        uint4 v2 = *(const uint4*)(Hb + o2 + fb);
        uint4 v3 = *(const uint4*)(Hb + o3 + fb);
        const unsigned* u0 = (const unsigned*)&v0;
        const unsigned* u1 = (const unsigned*)&v1;
        const unsigned* u2 = (const unsigned*)&v2;
        const unsigned* u3 = (const unsigned*)&v3;
#pragma unroll
        for (int k = 0; k < 4; ++k) {
            UNPK_ADD(accA[k], u0[k]);
            UNPK_ADD(accB[k], u1[k]);
            UNPK_ADD(accA[k], u2[k]);
            UNPK_ADD(accB[k], u3[k]);
        }
    }
    for (; j + 4 < e; j += 8) {
        unsigned o0 = (unsigned)cols[j];
        unsigned o1 = (unsigned)cols[j + 4];
        uint4 v0 = *(const uint4*)(Hb + o0 + fb);
        uint4 v1 = *(const uint4*)(Hb + o1 + fb);
        const unsigned* u0 = (const unsigned*)&v0;
        const unsigned* u1 = (const unsigned*)&v1;
#pragma unroll
        for (int k = 0; k < 4; ++k) {
            UNPK_ADD(accA[k], u0[k]);
            UNPK_ADD(accB[k], u1[k]);
        }
    }
    if (j < e) {
        unsigned o0 = (unsigned)cols[j];
        uint4 v0 = *(const uint4*)(Hb + o0 + fb);
        const unsigned* u0 = (const unsigned*)&v0;
#pragma unroll
        for (int k = 0; k < 4; ++k) UNPK_ADD(accA[k], u0[k]);
    }
#undef UNPK_ADD

    float acc[8];
#pragma unroll
    for (int k = 0; k < 4; ++k) {
        acc[2 * k]     = accA[k].x + accB[k].x;
        acc[2 * k + 1] = accA[k].y + accB[k].y;
    }
#pragma unroll
    for (int k = 0; k < 8; ++k) {
        acc[k] += __shfl_xor(acc[k], 16, 64);
        acc[k] += __shfl_xor(acc[k], 32, 64);
    }

    if (q == 0) {
        unsigned f = (lane & 15) << 3;
        float inv_i = inv[node];
        float4 b0 = *(const float4*)(bias + f);
        float4 b1v = *(const float4*)(bias + f + 4);
        *(float4*)(out + (size_t)node * NFEAT + f) =
            make_float4(acc[0] * inv_i + b0.x, acc[1] * inv_i + b0.y,
                        acc[2] * inv_i + b0.z, acc[3] * inv_i + b0.w);
        *(float4*)(out + (size_t)node * NFEAT + f + 4) =
            make_float4(acc[4] * inv_i + b1v.x, acc[5] * inv_i + b1v.y,
                        acc[6] * inv_i + b1v.z, acc[7] * inv_i + b1v.w);
    }
}

// ---------------- launch ----------------
static inline size_t align256(size_t x) { return (x + 255) & ~(size_t)255; }

extern "C" void kernel_launch(void* const* d_in, const int* in_sizes, int n_in,
                              void* d_out, int out_size, void* d_ws, size_t ws_size,
                              hipStream_t stream) {
    const float* x   = (const float*)d_in[0];
    const int*   ei  = (const int*)d_in[1];
    const float* W1  = (const float*)d_in[2];
    const float* b1  = (const float*)d_in[3];
    const float* W2  = (const float*)d_in[4];
    const float* b2  = (const float*)d_in[5];
    const float* W3  = (const float*)d_in[6];
    const float* b3  = (const float*)d_in[7];
    float* out = (float*)d_out;

    const int N = in_sizes[0] / NFEAT;
    const int E = in_sizes[1] / 2;
    const int* rows = ei;
    const int* colsIn = ei + E;

    const int nbk = (E + EPB - 1) / EPB;       // edge blocks
    const int nbu = (N + RPB - 1) / RPB;       // row buckets
    const int K = nbk * nbu;

    // workspace layout
    char* ws = (char*)d_ws;
    size_t off = 0;
    unsigned short* Hn = (unsigned short*)(ws + off);
    off = align256(off + (size_t)N * NFEAT * sizeof(unsigned short));
    unsigned short* Hn2 = (unsigned short*)(ws + off);
    off = align256(off + (size_t)N * NFEAT * sizeof(unsigned short));
    int*   bufA    = (int*)(ws + off);   off = align256(off + (size_t)K * sizeof(int));
    int*   bufB    = (int*)(ws + off);   off = align256(off + (size_t)K * sizeof(int));
    int*   bsums   = (int*)(ws + off);   off = align256(off + (size_t)256 * sizeof(int));
    int*   packed  = (int*)(ws + off);   off = align256(off + (size_t)E * sizeof(int));
    int*   colSort = (int*)(ws + off);   off = align256(off + (size_t)E * sizeof(int));
    int*   row_ptr = (int*)(ws + off);   off = align256(off + (size_t)(N + 1) * sizeof(int));
    float* inv     = (float*)(ws + off); off = align256(off + (size_t)N * sizeof(float));
    unsigned short* WtH = (unsigned short*)(ws + off);
    off = align256(off + (size_t)3 * NFEAT * NFEAT * sizeof(unsigned short));
    unsigned short* WtL = (unsigned short*)(ws + off);
    off = align256(off + (size_t)3 * NFEAT * NFEAT * sizeof(unsigned short));
    (void)ws_size; (void)n_in; (void)out_size;

    const int nb2 = (K + SCAN_B - 1) / SCAN_B;

    // --- W splits (one launch for all 3 layers) ---
    wsplit3_kernel<<<dim3(64, 3), 256, 0, stream>>>(W1, W2, W3, WtH, WtL);

    // --- CSR build (coalesced counting sort) ---
    a1_hist<<<nbk, 256, 0, stream>>>(rows, E, bufA, nbu);
    transpose_counts<<<(K + 255) / 256, 256, 0, stream>>>(bufA, bufB, nbk, nbu);
    scanA_kernel<<<nb2, SCAN_B, 0, stream>>>(bufB, K, bufA, bsums);
    scanB_kernel<<<1, 256, 0, stream>>>(bsums, nb2);
    a2_scatter<<<nbk, 256, 0, stream>>>(rows, colsIn, E, bufA, bsums, nbk, nbu, packed);
    b_sort<<<nbu, 256, 0, stream>>>(packed, bufA, bsums, nbk, nbu, N, E, colSort, row_ptr, inv);

    const int gemm_grid = (N + 63) / 64;
    const int fuse_grid = (N + 15) / 16;
    const int agg_grid  = (N + 3) / 4;

    // --- layer 1 GEMM ---
    gemm_mfma_f32<<<gemm_grid, 256, 0, stream>>>(x, WtH, WtL, inv, Hn, N);
    // --- agg(L1) + GEMM(L2) fused ---
    agg_gemm<<<fuse_grid, 256, 0, stream>>>(Hn, row_ptr, colSort, inv, b1,
                                            WtH + NFEAT * NFEAT, WtL + NFEAT * NFEAT, Hn2, N);
    // --- agg(L2) + GEMM(L3) fused ---
    agg_gemm<<<fuse_grid, 256, 0, stream>>>(Hn2, row_ptr, colSort, inv, b2,
                                            WtH + 2 * NFEAT * NFEAT, WtL + 2 * NFEAT * NFEAT, Hn, N);
    // --- final aggregation ---
    aggregate_final<<<agg_grid, 256, 0, stream>>>(Hn, row_ptr, colSort, inv, b3, out, N);
}

// Round 9
// 383.391 us; speedup vs baseline: 1.2678x; 1.2006x over previous
//
#include <hip/hip_runtime.h>
#include <hip/hip_bf16.h>

#define NFEAT 128
#define EPB   4096          // edges per A-block (16 per thread * 256)
#define RPB   256           // rows per bucket (bucket = row >> 8)
#define NBU_PAD 512
#define BCAP  6144          // bucket capacity in pass B (mean ~4092, +32 sigma)

typedef short bf16x8 __attribute__((ext_vector_type(8)));
typedef float f32x4  __attribute__((ext_vector_type(4)));

// ---------- Pass A1: per-block bucket histogram (LDS), coalesced write ----------
__global__ __launch_bounds__(256) void a1_hist(const int* __restrict__ rows, int E,
                                               int* __restrict__ countsT, int nbu) {
    __shared__ int h[NBU_PAD];
    int t = threadIdx.x;
    for (int i = t; i < NBU_PAD; i += 256) h[i] = 0;
    __syncthreads();
    int e0 = blockIdx.x * EPB;
    int ecnt = min(EPB, E - e0);
    for (int k = t; k < ecnt; k += 256) atomicAdd(&h[rows[e0 + k] >> 8], 1);
    __syncthreads();
    for (int j = t; j < nbu; j += 256) countsT[(size_t)blockIdx.x * nbu + j] = h[j];
}

// ---------- transpose counts [blk][b] -> [b][blk] (write-coalesced) ----------
__global__ void transpose_counts(const int* __restrict__ in, int* __restrict__ out,
                                 int nbk, int nbu) {
    int i = blockIdx.x * 256 + threadIdx.x;
    if (i < nbk * nbu) {
        int b = i / nbk, blk = i - b * nbk;
        out[i] = in[(size_t)blk * nbu + b];
    }
}

// ---------- flat exclusive scan: per-block pass ----------
#define SCAN_B 1024
__global__ void scanA_kernel(const int* __restrict__ in, int K,
                             int* __restrict__ excl, int* __restrict__ bsums) {
    __shared__ int sm[SCAN_B];
    int t = threadIdx.x;
    int g = blockIdx.x * SCAN_B + t;
    int v = (g < K) ? in[g] : 0;
    sm[t] = v;
    __syncthreads();
    for (int off = 1; off < SCAN_B; off <<= 1) {
        int u = (t >= off) ? sm[t - off] : 0;
        __syncthreads();
        sm[t] += u;
        __syncthreads();
    }
    if (g < K) excl[g] = sm[t] - v;
    if (t == SCAN_B - 1) bsums[blockIdx.x] = sm[t];
}

__global__ void scanB_kernel(int* __restrict__ bsums, int nb) {
    __shared__ int s[256];
    int t = threadIdx.x;
    int v = (t < nb) ? bsums[t] : 0;
    s[t] = v;
    __syncthreads();
    for (int off = 1; off < 256; off <<= 1) {
        int u = (t >= off) ? s[t - off] : 0;
        __syncthreads();
        s[t] += u;
        __syncthreads();
    }
    if (t < nb) bsums[t] = s[t] - v;
}

// ---------- Pass A2: LDS counting-sort block's edges by bucket, coalesced scatter ----------
// scanArr entries are block-local; global base = scanArr[idx] + bsums[idx>>10]
__global__ __launch_bounds__(256) void a2_scatter(const int* __restrict__ rows,
                                                  const int* __restrict__ colsIn, int E,
                                                  const int* __restrict__ scanArr,
                                                  const int* __restrict__ bsums,
                                                  int nbk, int nbu,
                                                  int* __restrict__ packed) {
    __shared__ int cnt[NBU_PAD], start[NBU_PAD], cur[NBU_PAD];
    __shared__ int sortedV[EPB];
    __shared__ unsigned short sortedB[EPB];
    __shared__ int p[256];
    int t = threadIdx.x, blk = blockIdx.x;
    for (int i = t; i < NBU_PAD; i += 256) cnt[i] = 0;
    __syncthreads();
    int e0 = blk * EPB;
    int ecnt = min(EPB, E - e0);
    int myr[16], myc[16];
#pragma unroll
    for (int k = 0; k < 16; ++k) {
        int idx = k * 256 + t;
        if (idx < ecnt) {
            myr[k] = rows[e0 + idx];
            myc[k] = colsIn[e0 + idx];
            atomicAdd(&cnt[myr[k] >> 8], 1);
        }
    }
    __syncthreads();
    int a0 = cnt[2 * t], a1 = cnt[2 * t + 1];
    p[t] = a0 + a1;
    __syncthreads();
    for (int off = 1; off < 256; off <<= 1) {
        int u = (t >= off) ? p[t - off] : 0;
        __syncthreads();
        p[t] += u;
        __syncthreads();
    }
    int ex = p[t] - (a0 + a1);
    start[2 * t] = ex;      start[2 * t + 1] = ex + a0;
    cur[2 * t] = ex;        cur[2 * t + 1] = ex + a0;
    __syncthreads();
#pragma unroll
    for (int k = 0; k < 16; ++k) {
        int idx = k * 256 + t;
        if (idx < ecnt) {
            int b = myr[k] >> 8;
            int pos = atomicAdd(&cur[b], 1);
            sortedV[pos] = ((myr[k] & 255) << 17) | myc[k];
            sortedB[pos] = (unsigned short)b;
        }
    }
    __syncthreads();
    for (int j = t; j < nbu; j += 256) {
        int idx = j * nbk + blk;
        cnt[j] = scanArr[idx] + bsums[idx >> 10] - start[j];
    }
    __syncthreads();
    for (int i = t; i < ecnt; i += 256) {
        int b = sortedB[i];
        packed[cnt[b] + i] = sortedV[i];
    }
}

// ---------- Pass B: per-bucket LDS sort by row; emit colSort (BYTE offsets), row_ptr, inv ----------
__global__ __launch_bounds__(256) void b_sort(const int* __restrict__ packed,
                                              const int* __restrict__ scanArr,
                                              const int* __restrict__ bsums,
                                              int nbk, int nbu, int N, int E,
                                              int* __restrict__ colSort,
                                              int* __restrict__ row_ptr,
                                              float* __restrict__ inv) {
    __shared__ int cnt[RPB], start[RPB], cur[RPB], s[RPB];
    __shared__ int sv[BCAP];
    int t = threadIdx.x, b = blockIdx.x;
    int i0 = b * nbk;
    int base = scanArr[i0] + bsums[i0 >> 10];
    int nxt;
    if (b + 1 < nbu) {
        int i1 = (b + 1) * nbk;
        nxt = scanArr[i1] + bsums[i1 >> 10];
    } else nxt = E;
    int sz = nxt - base;
    cnt[t] = 0;
    __syncthreads();
    for (int i = t; i < sz; i += 256) atomicAdd(&cnt[(packed[base + i] >> 17) & 255], 1);
    __syncthreads();
    int c = cnt[t];
    s[t] = c;
    __syncthreads();
    for (int off = 1; off < 256; off <<= 1) {
        int u = (t >= off) ? s[t - off] : 0;
        __syncthreads();
        s[t] += u;
        __syncthreads();
    }
    start[t] = s[t] - c;
    cur[t] = s[t] - c;
    __syncthreads();
    for (int i = t; i < sz; i += 256) {
        int v = packed[base + i];
        int lr = (v >> 17) & 255;
        int pos = atomicAdd(&cur[lr], 1);
        if (pos < BCAP) sv[pos] = v & 0x1FFFF;
    }
    __syncthreads();
    // emit byte offsets (col * 256 bytes per bf16 row)
    for (int i = t; i < sz; i += 256) colSort[base + i] = sv[i] << 8;
    int r = b * RPB + t;
    if (r < N) {
        row_ptr[r] = base + start[t];
        inv[r] = rsqrtf((float)(c + 1));
    }
    if (b == 0 && t == 0) row_ptr[N] = E;
}

// ---------- bf16 helpers ----------
__device__ inline unsigned short f2bf(float x) {
    unsigned u = __float_as_uint(x);
    unsigned r = (u + 0x7FFFu + ((u >> 16) & 1u)) >> 16;   // RNE
    return (unsigned short)r;
}

__device__ inline void split2(float x0, float x1, unsigned& hw, unsigned& lw) {
    unsigned u0 = __float_as_uint(x0), u1 = __float_as_uint(x1);
    hw = (u1 & 0xFFFF0000u) | (u0 >> 16);
    float l0 = x0 - __uint_as_float(u0 & 0xFFFF0000u);   // exact
    float l1 = x1 - __uint_as_float(u1 & 0xFFFF0000u);   // exact
    lw = (__float_as_uint(l1) & 0xFFFF0000u) | (__float_as_uint(l0) >> 16);
}

// ---------- W prep: Wt_hi/Wt_lo[w][c][k] (bf16, transposed), all 3 layers in one launch ----------
__global__ void wsplit3_kernel(const float* __restrict__ W1, const float* __restrict__ W2,
                               const float* __restrict__ W3,
                               unsigned short* __restrict__ WtH,
                               unsigned short* __restrict__ WtL) {
    int w = blockIdx.y;
    const float* W = (w == 0) ? W1 : (w == 1) ? W2 : W3;
    int i = blockIdx.x * 256 + threadIdx.x;   // i = c*128 + k
    int c = i >> 7, k = i & 127;
    float wv = W[k * NFEAT + c];
    unsigned u = __float_as_uint(wv);
    unsigned hib = u & 0xFFFF0000u;
    float lo = wv - __uint_as_float(hib);
    WtH[w * NFEAT * NFEAT + i] = (unsigned short)(u >> 16);
    WtL[w * NFEAT * NFEAT + i] = (unsigned short)(__float_as_uint(lo) >> 16);
}

// ---------------- MFMA GEMM (f32 input, in-reg split): layer 1 ----------------
__global__ __launch_bounds__(256) void gemm_mfma_f32(const float* __restrict__ X,
                                                     const unsigned short* __restrict__ Wt_hi,
                                                     const unsigned short* __restrict__ Wt_lo,
                                                     const float* __restrict__ inv,
                                                     unsigned short* __restrict__ Hn, int n) {
    int tid = threadIdx.x;
    int wave = tid >> 6, lane = tid & 63;
    int lrow = lane & 15, kgrp = lane >> 4;
    int wcol0 = wave * 32;
    int rowbase = blockIdx.x * 64;

    bf16x8 bh[2][4], bl[2][4];
#pragma unroll
    for (int ct = 0; ct < 2; ++ct) {
        int col = wcol0 + ct * 16 + lrow;
        const unsigned short* ph = Wt_hi + (size_t)col * NFEAT + kgrp * 8;
        const unsigned short* pl = Wt_lo + (size_t)col * NFEAT + kgrp * 8;
#pragma unroll
        for (int ks = 0; ks < 4; ++ks) {
            bh[ct][ks] = *(const bf16x8*)(ph + ks * 32);
            bl[ct][ks] = *(const bf16x8*)(pl + ks * 32);
        }
    }

    union U8 { bf16x8 v; unsigned w[4]; };

#pragma unroll
    for (int rt = 0; rt < 4; ++rt) {
        int arow = rowbase + rt * 16 + lrow;
        int rc = arow < n ? arow : n - 1;
        const float* px = X + (size_t)rc * NFEAT + kgrp * 8;

        bf16x8 ah[4], al[4];
#pragma unroll
        for (int ks = 0; ks < 4; ++ks) {
            float4 v0 = *(const float4*)(px + ks * 32);
            float4 v1 = *(const float4*)(px + ks * 32 + 4);
            U8 uh, ul;
            split2(v0.x, v0.y, uh.w[0], ul.w[0]);
            split2(v0.z, v0.w, uh.w[1], ul.w[1]);
            split2(v1.x, v1.y, uh.w[2], ul.w[2]);
            split2(v1.z, v1.w, uh.w[3], ul.w[3]);
            ah[ks] = uh.v;
            al[ks] = ul.v;
        }

        f32x4 acc[2] = {{0.f, 0.f, 0.f, 0.f}, {0.f, 0.f, 0.f, 0.f}};
#pragma unroll
        for (int ks = 0; ks < 4; ++ks) {
#pragma unroll
            for (int ct = 0; ct < 2; ++ct) {
                acc[ct] = __builtin_amdgcn_mfma_f32_16x16x32_bf16(ah[ks], bh[ct][ks], acc[ct], 0, 0, 0);
                acc[ct] = __builtin_amdgcn_mfma_f32_16x16x32_bf16(ah[ks], bl[ct][ks], acc[ct], 0, 0, 0);
                acc[ct] = __builtin_amdgcn_mfma_f32_16x16x32_bf16(al[ks], bh[ct][ks], acc[ct], 0, 0, 0);
            }
        }

#pragma unroll
        for (int m = 0; m < 4; ++m) {
            int orow = rowbase + rt * 16 + kgrp * 4 + m;
            if (orow < n) {
                float sc = inv[orow];
#pragma unroll
                for (int ct = 0; ct < 2; ++ct) {
                    int col = wcol0 + ct * 16 + lrow;
                    Hn[(size_t)orow * NFEAT + col] = f2bf(acc[ct][m] * sc);
                }
            }
        }
    }
}

// ---------------- MFMA GEMM (pre-split bf16 input): layers 2,3 ----------------
__global__ __launch_bounds__(256) void gemm_mfma_bf16(const unsigned short* __restrict__ XH,
                                                      const unsigned short* __restrict__ XL,
                                                      const unsigned short* __restrict__ Wt_hi,
                                                      const unsigned short* __restrict__ Wt_lo,
                                                      const float* __restrict__ inv,
                                                      unsigned short* __restrict__ Hn, int n) {
    int tid = threadIdx.x;
    int wave = tid >> 6, lane = tid & 63;
    int lrow = lane & 15, kgrp = lane >> 4;
    int wcol0 = wave * 32;
    int rowbase = blockIdx.x * 64;

    bf16x8 bh[2][4], bl[2][4];
#pragma unroll
    for (int ct = 0; ct < 2; ++ct) {
        int col = wcol0 + ct * 16 + lrow;
        const unsigned short* ph = Wt_hi + (size_t)col * NFEAT + kgrp * 8;
        const unsigned short* pl = Wt_lo + (size_t)col * NFEAT + kgrp * 8;
#pragma unroll
        for (int ks = 0; ks < 4; ++ks) {
            bh[ct][ks] = *(const bf16x8*)(ph + ks * 32);
            bl[ct][ks] = *(const bf16x8*)(pl + ks * 32);
        }
    }

#pragma unroll
    for (int rt = 0; rt < 4; ++rt) {
        int arow = rowbase + rt * 16 + lrow;
        int rc = arow < n ? arow : n - 1;
        const unsigned short* pxh = XH + (size_t)rc * NFEAT + kgrp * 8;
        const unsigned short* pxl = XL + (size_t)rc * NFEAT + kgrp * 8;

        bf16x8 ah[4], al[4];
#pragma unroll
        for (int ks = 0; ks < 4; ++ks) {
            ah[ks] = *(const bf16x8*)(pxh + ks * 32);
            al[ks] = *(const bf16x8*)(pxl + ks * 32);
        }

        f32x4 acc[2] = {{0.f, 0.f, 0.f, 0.f}, {0.f, 0.f, 0.f, 0.f}};
#pragma unroll
        for (int ks = 0; ks < 4; ++ks) {
#pragma unroll
            for (int ct = 0; ct < 2; ++ct) {
                acc[ct] = __builtin_amdgcn_mfma_f32_16x16x32_bf16(ah[ks], bh[ct][ks], acc[ct], 0, 0, 0);
                acc[ct] = __builtin_amdgcn_mfma_f32_16x16x32_bf16(ah[ks], bl[ct][ks], acc[ct], 0, 0, 0);
                acc[ct] = __builtin_amdgcn_mfma_f32_16x16x32_bf16(al[ks], bh[ct][ks], acc[ct], 0, 0, 0);
            }
        }

#pragma unroll
        for (int m = 0; m < 4; ++m) {
            int orow = rowbase + rt * 16 + kgrp * 4 + m;
            if (orow < n) {
                float sc = inv[orow];
#pragma unroll
                for (int ct = 0; ct < 2; ++ct) {
                    int col = wcol0 + ct * 16 + lrow;
                    Hn[(size_t)orow * NFEAT + col] = f2bf(acc[ct][m] * sc);
                }
            }
        }
    }
}

// ---------------- Aggregation (bf16 gather, 4-deep, float2 accum) ----------------
// cols[] holds BYTE offsets (col*256). One wave/node; quarter-wave (16 lanes x 16B) per edge.
// Self-loop rides on quarter 3 (fewest edges when deg%4<3).
template <int RELU, int EMIT_SPLIT>
__global__ __launch_bounds__(256) void aggregate_bf16(const unsigned short* __restrict__ Hn,
                                                      const int* __restrict__ row_ptr,
                                                      const int* __restrict__ cols,
                                                      const float* __restrict__ inv,
                                                      const float* __restrict__ bias,
                                                      float* __restrict__ out,
                                                      unsigned short* __restrict__ XH,
                                                      unsigned short* __restrict__ XL, int n) {
    int node = blockIdx.x * (blockDim.x >> 6) + (threadIdx.x >> 6);
    if (node >= n) return;
    int lane = threadIdx.x & 63;
    int q = lane >> 4;                 // quarter id 0..3
    unsigned fb = (lane & 15) << 4;    // byte offset within row (16 B per lane)
    const char* Hb = (const char*)Hn;

    float2 accA[4], accB[4];
#pragma unroll
    for (int k = 0; k < 4; ++k) {
        accA[k] = make_float2(0.f, 0.f);
        accB[k] = make_float2(0.f, 0.f);
    }

#define UNPK_ADD(ACC, W) do {                                              \
        unsigned _w = (W);                                                 \
        (ACC).x += __uint_as_float(_w << 16);                              \
        (ACC).y += __uint_as_float(_w & 0xFFFF0000u);                      \
    } while (0)

    if (q == 3) {  // self loop term
        uint4 v = *(const uint4*)(Hb + ((unsigned)node << 8) + fb);
        const unsigned* u = (const unsigned*)&v;
#pragma unroll
        for (int k = 0; k < 4; ++k) UNPK_ADD(accA[k], u[k]);
    }

    int s = row_ptr[node], e = row_ptr[node + 1];
    int j = s + q;
    // 4-deep: four gathers in flight per quarter-wave (16 edges/iter per wave)
    for (; j + 12 < e; j += 16) {
        unsigned o0 = (unsigned)cols[j];
        unsigned o1 = (unsigned)cols[j + 4];
        unsigned o2 = (unsigned)cols[j + 8];
        unsigned o3 = (unsigned)cols[j + 12];
        uint4 v0 = *(const uint4*)(Hb + o0 + fb);
        uint4 v1 = *(const uint4*)(Hb + o1 + fb);
        uint4 v2 = *(const uint4*)(Hb + o2 + fb);
        uint4 v3 = *(const uint4*)(Hb + o3 + fb);
        const unsigned* u0 = (const unsigned*)&v0;
        const unsigned* u1 = (const unsigned*)&v1;
        const unsigned* u2 = (const unsigned*)&v2;
        const unsigned* u3 = (const unsigned*)&v3;
#pragma unroll
        for (int k = 0; k < 4; ++k) {
            UNPK_ADD(accA[k], u0[k]);
            UNPK_ADD(accB[k], u1[k]);
            UNPK_ADD(accA[k], u2[k]);
            UNPK_ADD(accB[k], u3[k]);
        }
    }
    // 2-deep mid
    for (; j + 4 < e; j += 8) {
        unsigned o0 = (unsigned)cols[j];
        unsigned o1 = (unsigned)cols[j + 4];
        uint4 v0 = *(const uint4*)(Hb + o0 + fb);
        uint4 v1 = *(const uint4*)(Hb + o1 + fb);
        const unsigned* u0 = (const unsigned*)&v0;
        const unsigned* u1 = (const unsigned*)&v1;
#pragma unroll
        for (int k = 0; k < 4; ++k) {
            UNPK_ADD(accA[k], u0[k]);
            UNPK_ADD(accB[k], u1[k]);
        }
    }
    if (j < e) {
        unsigned o0 = (unsigned)cols[j];
        uint4 v0 = *(const uint4*)(Hb + o0 + fb);
        const unsigned* u0 = (const unsigned*)&v0;
#pragma unroll
        for (int k = 0; k < 4; ++k) UNPK_ADD(accA[k], u0[k]);
    }
#undef UNPK_ADD

    float acc[8];
#pragma unroll
    for (int k = 0; k < 4; ++k) {
        acc[2 * k]     = accA[k].x + accB[k].x;
        acc[2 * k + 1] = accA[k].y + accB[k].y;
    }

#pragma unroll
    for (int k = 0; k < 8; ++k) {
        acc[k] += __shfl_xor(acc[k], 16, 64);
        acc[k] += __shfl_xor(acc[k], 32, 64);
    }

    if (q == 0) {
        unsigned f = (lane & 15) << 3;   // feature index (floats/shorts)
        float inv_i = inv[node];
        float4 b0 = *(const float4*)(bias + f);
        float4 b1v = *(const float4*)(bias + f + 4);
        float r[8];
        r[0] = acc[0] * inv_i + b0.x; r[1] = acc[1] * inv_i + b0.y;
        r[2] = acc[2] * inv_i + b0.z; r[3] = acc[3] * inv_i + b0.w;
        r[4] = acc[4] * inv_i + b1v.x; r[5] = acc[5] * inv_i + b1v.y;
        r[6] = acc[6] * inv_i + b1v.z; r[7] = acc[7] * inv_i + b1v.w;
        if (RELU) {
#pragma unroll
            for (int k = 0; k < 8; ++k) r[k] = fmaxf(r[k], 0.f);
        }
        if (EMIT_SPLIT) {
            ushort4 hv[2], lv[2];
#pragma unroll
            for (int g = 0; g < 2; ++g) {
#pragma unroll
                for (int k = 0; k < 4; ++k) {
                    float y = r[g * 4 + k];
                    unsigned u = __float_as_uint(y);
                    unsigned short hb = (unsigned short)(u >> 16);
                    float lo = y - __uint_as_float(u & 0xFFFF0000u);
                    ((unsigned short*)&hv[g])[k] = hb;
                    ((unsigned short*)&lv[g])[k] = f2bf(lo);
                }
            }
            *(ushort4*)(XH + (size_t)node * NFEAT + f)     = hv[0];
            *(ushort4*)(XH + (size_t)node * NFEAT + f + 4) = hv[1];
            *(ushort4*)(XL + (size_t)node * NFEAT + f)     = lv[0];
            *(ushort4*)(XL + (size_t)node * NFEAT + f + 4) = lv[1];
        } else {
            *(float4*)(out + (size_t)node * NFEAT + f)     = make_float4(r[0], r[1], r[2], r[3]);
            *(float4*)(out + (size_t)node * NFEAT + f + 4) = make_float4(r[4], r[5], r[6], r[7]);
        }
    }
}

// ---------------- launch ----------------
static inline size_t align256(size_t x) { return (x + 255) & ~(size_t)255; }

extern "C" void kernel_launch(void* const* d_in, const int* in_sizes, int n_in,
                              void* d_out, int out_size, void* d_ws, size_t ws_size,
                              hipStream_t stream) {
    const float* x   = (const float*)d_in[0];
    const int*   ei  = (const int*)d_in[1];
    const float* W1  = (const float*)d_in[2];
    const float* b1  = (const float*)d_in[3];
    const float* W2  = (const float*)d_in[4];
    const float* b2  = (const float*)d_in[5];
    const float* W3  = (const float*)d_in[6];
    const float* b3  = (const float*)d_in[7];
    float* out = (float*)d_out;

    const int N = in_sizes[0] / NFEAT;
    const int E = in_sizes[1] / 2;
    const int* rows = ei;
    const int* colsIn = ei + E;

    const int nbk = (E + EPB - 1) / EPB;       // edge blocks
    const int nbu = (N + RPB - 1) / RPB;       // row buckets
    const int K = nbk * nbu;

    // workspace layout
    char* ws = (char*)d_ws;
    size_t off = 0;
    unsigned short* Hn = (unsigned short*)(ws + off);
    off = align256(off + (size_t)N * NFEAT * sizeof(unsigned short));
    unsigned short* XH = (unsigned short*)(ws + off);
    off = align256(off + (size_t)N * NFEAT * sizeof(unsigned short));
    unsigned short* XL = (unsigned short*)(ws + off);
    off = align256(off + (size_t)N * NFEAT * sizeof(unsigned short));
    int*   bufA    = (int*)(ws + off);   off = align256(off + (size_t)K * sizeof(int));
    int*   bufB    = (int*)(ws + off);   off = align256(off + (size_t)K * sizeof(int));
    int*   bsums   = (int*)(ws + off);   off = align256(off + (size_t)256 * sizeof(int));
    int*   packed  = (int*)(ws + off);   off = align256(off + (size_t)E * sizeof(int));
    int*   colSort = (int*)(ws + off);   off = align256(off + (size_t)E * sizeof(int));
    int*   row_ptr = (int*)(ws + off);   off = align256(off + (size_t)(N + 1) * sizeof(int));
    float* inv     = (float*)(ws + off); off = align256(off + (size_t)N * sizeof(float));
    unsigned short* WtH = (unsigned short*)(ws + off);
    off = align256(off + (size_t)3 * NFEAT * NFEAT * sizeof(unsigned short));
    unsigned short* WtL = (unsigned short*)(ws + off);
    off = align256(off + (size_t)3 * NFEAT * NFEAT * sizeof(unsigned short));
    (void)ws_size; (void)n_in; (void)out_size;

    const int nb2 = (K + SCAN_B - 1) / SCAN_B;

    // --- W splits (one launch for all 3 layers) ---
    wsplit3_kernel<<<dim3(64, 3), 256, 0, stream>>>(W1, W2, W3, WtH, WtL);

    // --- CSR build (coalesced counting sort) ---
    a1_hist<<<nbk, 256, 0, stream>>>(rows, E, bufA, nbu);
    transpose_counts<<<(K + 255) / 256, 256, 0, stream>>>(bufA, bufB, nbk, nbu);
    scanA_kernel<<<nb2, SCAN_B, 0, stream>>>(bufB, K, bufA, bsums);
    scanB_kernel<<<1, 256, 0, stream>>>(bsums, nb2);
    a2_scatter<<<nbk, 256, 0, stream>>>(rows, colsIn, E, bufA, bsums, nbk, nbu, packed);
    b_sort<<<nbu, 256, 0, stream>>>(packed, bufA, bsums, nbk, nbu, N, E, colSort, row_ptr, inv);

    const int gemm_grid = (N + 63) / 64;
    const int agg_grid  = (N + 3) / 4;

    // --- layer 1 ---
    gemm_mfma_f32<<<gemm_grid, 256, 0, stream>>>(x, WtH, WtL, inv, Hn, N);
    aggregate_bf16<1, 1><<<agg_grid, 256, 0, stream>>>(Hn, row_ptr, colSort, inv, b1,
                                                       nullptr, XH, XL, N);
    // --- layer 2 ---
    gemm_mfma_bf16<<<gemm_grid, 256, 0, stream>>>(XH, XL, WtH + NFEAT * NFEAT, WtL + NFEAT * NFEAT,
                                                  inv, Hn, N);
    aggregate_bf16<1, 1><<<agg_grid, 256, 0, stream>>>(Hn, row_ptr, colSort, inv, b2,
                                                       nullptr, XH, XL, N);
    // --- layer 3 ---
    gemm_mfma_bf16<<<gemm_grid, 256, 0, stream>>>(XH, XL, WtH + 2 * NFEAT * NFEAT,
                                                  WtL + 2 * NFEAT * NFEAT, inv, Hn, N);
    aggregate_bf16<0, 0><<<agg_grid, 256, 0, stream>>>(Hn, row_ptr, colSort, inv, b3,
                                                       out, nullptr, nullptr, N);
}

// Round 10
// 373.794 us; speedup vs baseline: 1.3003x; 1.0257x over previous
//
#include <hip/hip_runtime.h>
#include <hip/hip_bf16.h>

#define NFEAT 128
#define EPB   4096          // edges per A-block (16 per thread * 256)
#define RPB   256           // rows per bucket (bucket = row >> 8)
#define NBU_PAD 512
#define BCAP  6144          // bucket capacity in pass B (mean ~4092, +32 sigma)

typedef short bf16x8 __attribute__((ext_vector_type(8)));
typedef float f32x4  __attribute__((ext_vector_type(4)));

// ---------- Pass A1: per-block bucket histogram (LDS), coalesced write ----------
__global__ __launch_bounds__(256) void a1_hist(const int* __restrict__ rows, int E,
                                               int* __restrict__ countsT, int nbu) {
    __shared__ int h[NBU_PAD];
    int t = threadIdx.x;
    for (int i = t; i < NBU_PAD; i += 256) h[i] = 0;
    __syncthreads();
    int e0 = blockIdx.x * EPB;
    int ecnt = min(EPB, E - e0);
    for (int k = t; k < ecnt; k += 256) atomicAdd(&h[rows[e0 + k] >> 8], 1);
    __syncthreads();
    for (int j = t; j < nbu; j += 256) countsT[(size_t)blockIdx.x * nbu + j] = h[j];
}

// ---------- transpose counts [blk][b] -> [b][blk] (write-coalesced) ----------
__global__ void transpose_counts(const int* __restrict__ in, int* __restrict__ out,
                                 int nbk, int nbu) {
    int i = blockIdx.x * 256 + threadIdx.x;
    if (i < nbk * nbu) {
        int b = i / nbk, blk = i - b * nbk;
        out[i] = in[(size_t)blk * nbu + b];
    }
}

// ---------- flat exclusive scan: per-block pass ----------
#define SCAN_B 1024
__global__ void scanA_kernel(const int* __restrict__ in, int K,
                             int* __restrict__ excl, int* __restrict__ bsums) {
    __shared__ int sm[SCAN_B];
    int t = threadIdx.x;
    int g = blockIdx.x * SCAN_B + t;
    int v = (g < K) ? in[g] : 0;
    sm[t] = v;
    __syncthreads();
    for (int off = 1; off < SCAN_B; off <<= 1) {
        int u = (t >= off) ? sm[t - off] : 0;
        __syncthreads();
        sm[t] += u;
        __syncthreads();
    }
    if (g < K) excl[g] = sm[t] - v;
    if (t == SCAN_B - 1) bsums[blockIdx.x] = sm[t];
}

__global__ void scanB_kernel(int* __restrict__ bsums, int nb) {
    __shared__ int s[256];
    int t = threadIdx.x;
    int v = (t < nb) ? bsums[t] : 0;
    s[t] = v;
    __syncthreads();
    for (int off = 1; off < 256; off <<= 1) {
        int u = (t >= off) ? s[t - off] : 0;
        __syncthreads();
        s[t] += u;
        __syncthreads();
    }
    if (t < nb) bsums[t] = s[t] - v;
}

// ---------- Pass A2: LDS counting-sort block's edges by bucket, coalesced scatter ----------
// scanArr entries are block-local; global base = scanArr[idx] + bsums[idx>>10]
__global__ __launch_bounds__(256) void a2_scatter(const int* __restrict__ rows,
                                                  const int* __restrict__ colsIn, int E,
                                                  const int* __restrict__ scanArr,
                                                  const int* __restrict__ bsums,
                                                  int nbk, int nbu,
                                                  int* __restrict__ packed) {
    __shared__ int cnt[NBU_PAD], start[NBU_PAD], cur[NBU_PAD];
    __shared__ int sortedV[EPB];
    __shared__ unsigned short sortedB[EPB];
    __shared__ int p[256];
    int t = threadIdx.x, blk = blockIdx.x;
    for (int i = t; i < NBU_PAD; i += 256) cnt[i] = 0;
    __syncthreads();
    int e0 = blk * EPB;
    int ecnt = min(EPB, E - e0);
    int myr[16], myc[16];
#pragma unroll
    for (int k = 0; k < 16; ++k) {
        int idx = k * 256 + t;
        if (idx < ecnt) {
            myr[k] = rows[e0 + idx];
            myc[k] = colsIn[e0 + idx];
            atomicAdd(&cnt[myr[k] >> 8], 1);
        }
    }
    __syncthreads();
    int a0 = cnt[2 * t], a1 = cnt[2 * t + 1];
    p[t] = a0 + a1;
    __syncthreads();
    for (int off = 1; off < 256; off <<= 1) {
        int u = (t >= off) ? p[t - off] : 0;
        __syncthreads();
        p[t] += u;
        __syncthreads();
    }
    int ex = p[t] - (a0 + a1);
    start[2 * t] = ex;      start[2 * t + 1] = ex + a0;
    cur[2 * t] = ex;        cur[2 * t + 1] = ex + a0;
    __syncthreads();
#pragma unroll
    for (int k = 0; k < 16; ++k) {
        int idx = k * 256 + t;
        if (idx < ecnt) {
            int b = myr[k] >> 8;
            int pos = atomicAdd(&cur[b], 1);
            sortedV[pos] = ((myr[k] & 255) << 17) | myc[k];
            sortedB[pos] = (unsigned short)b;
        }
    }
    __syncthreads();
    for (int j = t; j < nbu; j += 256) {
        int idx = j * nbk + blk;
        cnt[j] = scanArr[idx] + bsums[idx >> 10] - start[j];
    }
    __syncthreads();
    for (int i = t; i < ecnt; i += 256) {
        int b = sortedB[i];
        packed[cnt[b] + i] = sortedV[i];
    }
}

// ---------- Pass B: per-bucket LDS sort by row; emit colSort (BYTE offsets), row_ptr, inv ----------
__global__ __launch_bounds__(256) void b_sort(const int* __restrict__ packed,
                                              const int* __restrict__ scanArr,
                                              const int* __restrict__ bsums,
                                              int nbk, int nbu, int N, int E,
                                              int* __restrict__ colSort,
                                              int* __restrict__ row_ptr,
                                              float* __restrict__ inv) {
    __shared__ int cnt[RPB], start[RPB], cur[RPB], s[RPB];
    __shared__ int sv[BCAP];
    int t = threadIdx.x, b = blockIdx.x;
    int i0 = b * nbk;
    int base = scanArr[i0] + bsums[i0 >> 10];
    int nxt;
    if (b + 1 < nbu) {
        int i1 = (b + 1) * nbk;
        nxt = scanArr[i1] + bsums[i1 >> 10];
    } else nxt = E;
    int sz = nxt - base;
    cnt[t] = 0;
    __syncthreads();
    for (int i = t; i < sz; i += 256) atomicAdd(&cnt[(packed[base + i] >> 17) & 255], 1);
    __syncthreads();
    int c = cnt[t];
    s[t] = c;
    __syncthreads();
    for (int off = 1; off < 256; off <<= 1) {
        int u = (t >= off) ? s[t - off] : 0;
        __syncthreads();
        s[t] += u;
        __syncthreads();
    }
    start[t] = s[t] - c;
    cur[t] = s[t] - c;
    __syncthreads();
    for (int i = t; i < sz; i += 256) {
        int v = packed[base + i];
        int lr = (v >> 17) & 255;
        int pos = atomicAdd(&cur[lr], 1);
        if (pos < BCAP) sv[pos] = v & 0x1FFFF;
    }
    __syncthreads();
    // emit byte offsets (col * 256 bytes per bf16 row)
    for (int i = t; i < sz; i += 256) colSort[base + i] = sv[i] << 8;
    int r = b * RPB + t;
    if (r < N) {
        row_ptr[r] = base + start[t];
        inv[r] = rsqrtf((float)(c + 1));
    }
    if (b == 0 && t == 0) row_ptr[N] = E;
}

// ---------- bf16 helpers ----------
__device__ inline unsigned short f2bf(float x) {
    unsigned u = __float_as_uint(x);
    unsigned r = (u + 0x7FFFu + ((u >> 16) & 1u)) >> 16;   // RNE
    return (unsigned short)r;
}

// packed RNE convert: lo16 = bf16(a), hi16 = bf16(b) — single VALU instr
__device__ inline unsigned cvt_pk_bf16(float a, float b) {
    unsigned r;
    asm("v_cvt_pk_bf16_f32 %0, %1, %2" : "=v"(r) : "v"(a), "v"(b));
    return r;
}

__device__ inline void split2(float x0, float x1, unsigned& hw, unsigned& lw) {
    unsigned u0 = __float_as_uint(x0), u1 = __float_as_uint(x1);
    hw = (u1 & 0xFFFF0000u) | (u0 >> 16);
    float l0 = x0 - __uint_as_float(u0 & 0xFFFF0000u);   // exact
    float l1 = x1 - __uint_as_float(u1 & 0xFFFF0000u);   // exact
    lw = (__float_as_uint(l1) & 0xFFFF0000u) | (__float_as_uint(l0) >> 16);
}

// ---------- W prep: Wt_hi/Wt_lo[w][c][k] (bf16, transposed), all 3 layers in one launch ----------
__global__ void wsplit3_kernel(const float* __restrict__ W1, const float* __restrict__ W2,
                               const float* __restrict__ W3,
                               unsigned short* __restrict__ WtH,
                               unsigned short* __restrict__ WtL) {
    int w = blockIdx.y;
    const float* W = (w == 0) ? W1 : (w == 1) ? W2 : W3;
    int i = blockIdx.x * 256 + threadIdx.x;   // i = c*128 + k
    int c = i >> 7, k = i & 127;
    float wv = W[k * NFEAT + c];
    unsigned u = __float_as_uint(wv);
    unsigned hib = u & 0xFFFF0000u;
    float lo = wv - __uint_as_float(hib);
    WtH[w * NFEAT * NFEAT + i] = (unsigned short)(u >> 16);
    WtL[w * NFEAT * NFEAT + i] = (unsigned short)(__float_as_uint(lo) >> 16);
}

// ---------------- MFMA GEMM (f32 input, in-reg split): layer 1 ----------------
// SWAPPED operands: mfma(W-frag, X-frag) -> lane owns (row=xrow, cols kgrp*4+m)
// -> one 8B store + 2 cvt_pk per (rt, ct).
__global__ __launch_bounds__(256) void gemm_mfma_f32(const float* __restrict__ X,
                                                     const unsigned short* __restrict__ Wt_hi,
                                                     const unsigned short* __restrict__ Wt_lo,
                                                     const float* __restrict__ inv,
                                                     unsigned short* __restrict__ Hn, int n) {
    int tid = threadIdx.x;
    int wave = tid >> 6, lane = tid & 63;
    int lrow = lane & 15, kgrp = lane >> 4;
    int wcol0 = wave * 32;
    int rowbase = blockIdx.x * 64;

    bf16x8 wh[2][4], wl[2][4];
#pragma unroll
    for (int ct = 0; ct < 2; ++ct) {
        int col = wcol0 + ct * 16 + lrow;
        const unsigned short* ph = Wt_hi + (size_t)col * NFEAT + kgrp * 8;
        const unsigned short* pl = Wt_lo + (size_t)col * NFEAT + kgrp * 8;
#pragma unroll
        for (int ks = 0; ks < 4; ++ks) {
            wh[ct][ks] = *(const bf16x8*)(ph + ks * 32);
            wl[ct][ks] = *(const bf16x8*)(pl + ks * 32);
        }
    }

    union U8 { bf16x8 v; unsigned w[4]; };

#pragma unroll
    for (int rt = 0; rt < 4; ++rt) {
        int arow = rowbase + rt * 16 + lrow;
        int rc = arow < n ? arow : n - 1;
        const float* px = X + (size_t)rc * NFEAT + kgrp * 8;

        bf16x8 xh[4], xl[4];
#pragma unroll
        for (int ks = 0; ks < 4; ++ks) {
            float4 v0 = *(const float4*)(px + ks * 32);
            float4 v1 = *(const float4*)(px + ks * 32 + 4);
            U8 uh, ul;
            split2(v0.x, v0.y, uh.w[0], ul.w[0]);
            split2(v0.z, v0.w, uh.w[1], ul.w[1]);
            split2(v1.x, v1.y, uh.w[2], ul.w[2]);
            split2(v1.z, v1.w, uh.w[3], ul.w[3]);
            xh[ks] = uh.v;
            xl[ks] = ul.v;
        }

        f32x4 acc[2] = {{0.f, 0.f, 0.f, 0.f}, {0.f, 0.f, 0.f, 0.f}};
#pragma unroll
        for (int ks = 0; ks < 4; ++ks) {
#pragma unroll
            for (int ct = 0; ct < 2; ++ct) {
                acc[ct] = __builtin_amdgcn_mfma_f32_16x16x32_bf16(wh[ct][ks], xh[ks], acc[ct], 0, 0, 0);
                acc[ct] = __builtin_amdgcn_mfma_f32_16x16x32_bf16(wl[ct][ks], xh[ks], acc[ct], 0, 0, 0);
                acc[ct] = __builtin_amdgcn_mfma_f32_16x16x32_bf16(wh[ct][ks], xl[ks], acc[ct], 0, 0, 0);
            }
        }

        // D mapping after swap: lane holds (X@W)[xrow = rowbase+rt*16+lrow][wcol0+ct*16+kgrp*4+m]
        int xrow = rowbase + rt * 16 + lrow;
        if (xrow < n) {
            float sc = inv[xrow];
#pragma unroll
            for (int ct = 0; ct < 2; ++ct) {
                uint2 st;
                st.x = cvt_pk_bf16(acc[ct][0] * sc, acc[ct][1] * sc);
                st.y = cvt_pk_bf16(acc[ct][2] * sc, acc[ct][3] * sc);
                *(uint2*)(Hn + (size_t)xrow * NFEAT + wcol0 + ct * 16 + kgrp * 4) = st;
            }
        }
    }
}

// ---------------- MFMA GEMM (pre-split bf16 input): layers 2,3 — swapped operands ----------------
__global__ __launch_bounds__(256) void gemm_mfma_bf16(const unsigned short* __restrict__ XH,
                                                      const unsigned short* __restrict__ XL,
                                                      const unsigned short* __restrict__ Wt_hi,
                                                      const unsigned short* __restrict__ Wt_lo,
                                                      const float* __restrict__ inv,
                                                      unsigned short* __restrict__ Hn, int n) {
    int tid = threadIdx.x;
    int wave = tid >> 6, lane = tid & 63;
    int lrow = lane & 15, kgrp = lane >> 4;
    int wcol0 = wave * 32;
    int rowbase = blockIdx.x * 64;

    bf16x8 wh[2][4], wl[2][4];
#pragma unroll
    for (int ct = 0; ct < 2; ++ct) {
        int col = wcol0 + ct * 16 + lrow;
        const unsigned short* ph = Wt_hi + (size_t)col * NFEAT + kgrp * 8;
        const unsigned short* pl = Wt_lo + (size_t)col * NFEAT + kgrp * 8;
#pragma unroll
        for (int ks = 0; ks < 4; ++ks) {
            wh[ct][ks] = *(const bf16x8*)(ph + ks * 32);
            wl[ct][ks] = *(const bf16x8*)(pl + ks * 32);
        }
    }

#pragma unroll
    for (int rt = 0; rt < 4; ++rt) {
        int arow = rowbase + rt * 16 + lrow;
        int rc = arow < n ? arow : n - 1;
        const unsigned short* pxh = XH + (size_t)rc * NFEAT + kgrp * 8;
        const unsigned short* pxl = XL + (size_t)rc * NFEAT + kgrp * 8;

        bf16x8 xh[4], xl[4];
#pragma unroll
        for (int ks = 0; ks < 4; ++ks) {
            xh[ks] = *(const bf16x8*)(pxh + ks * 32);
            xl[ks] = *(const bf16x8*)(pxl + ks * 32);
        }

        f32x4 acc[2] = {{0.f, 0.f, 0.f, 0.f}, {0.f, 0.f, 0.f, 0.f}};
#pragma unroll
        for (int ks = 0; ks < 4; ++ks) {
#pragma unroll
            for (int ct = 0; ct < 2; ++ct) {
                acc[ct] = __builtin_amdgcn_mfma_f32_16x16x32_bf16(wh[ct][ks], xh[ks], acc[ct], 0, 0, 0);
                acc[ct] = __builtin_amdgcn_mfma_f32_16x16x32_bf16(wl[ct][ks], xh[ks], acc[ct], 0, 0, 0);
                acc[ct] = __builtin_amdgcn_mfma_f32_16x16x32_bf16(wh[ct][ks], xl[ks], acc[ct], 0, 0, 0);
            }
        }

        int xrow = rowbase + rt * 16 + lrow;
        if (xrow < n) {
            float sc = inv[xrow];
#pragma unroll
            for (int ct = 0; ct < 2; ++ct) {
                uint2 st;
                st.x = cvt_pk_bf16(acc[ct][0] * sc, acc[ct][1] * sc);
                st.y = cvt_pk_bf16(acc[ct][2] * sc, acc[ct][3] * sc);
                *(uint2*)(Hn + (size_t)xrow * NFEAT + wcol0 + ct * 16 + kgrp * 4) = st;
            }
        }
    }
}

// ---------------- Aggregation (bf16 gather, 4-deep, float2 accum) ----------------
// cols[] holds BYTE offsets (col*256). One wave/node; quarter-wave (16 lanes x 16B) per edge.
// Self-loop rides on quarter 3 (fewest edges when deg%4<3).
template <int RELU, int EMIT_SPLIT>
__global__ __launch_bounds__(256) void aggregate_bf16(const unsigned short* __restrict__ Hn,
                                                      const int* __restrict__ row_ptr,
                                                      const int* __restrict__ cols,
                                                      const float* __restrict__ inv,
                                                      const float* __restrict__ bias,
                                                      float* __restrict__ out,
                                                      unsigned short* __restrict__ XH,
                                                      unsigned short* __restrict__ XL, int n) {
    int node = blockIdx.x * (blockDim.x >> 6) + (threadIdx.x >> 6);
    if (node >= n) return;
    int lane = threadIdx.x & 63;
    int q = lane >> 4;                 // quarter id 0..3
    unsigned fb = (lane & 15) << 4;    // byte offset within row (16 B per lane)
    const char* Hb = (const char*)Hn;

    float2 accA[4], accB[4];
#pragma unroll
    for (int k = 0; k < 4; ++k) {
        accA[k] = make_float2(0.f, 0.f);
        accB[k] = make_float2(0.f, 0.f);
    }

#define UNPK_ADD(ACC, W) do {                                              \
        unsigned _w = (W);                                                 \
        (ACC).x += __uint_as_float(_w << 16);                              \
        (ACC).y += __uint_as_float(_w & 0xFFFF0000u);                      \
    } while (0)

    if (q == 3) {  // self loop term
        uint4 v = *(const uint4*)(Hb + ((unsigned)node << 8) + fb);
        const unsigned* u = (const unsigned*)&v;
#pragma unroll
        for (int k = 0; k < 4; ++k) UNPK_ADD(accA[k], u[k]);
    }

    int s = row_ptr[node], e = row_ptr[node + 1];
    int j = s + q;
    // 4-deep: four gathers in flight per quarter-wave (16 edges/iter per wave)
    for (; j + 12 < e; j += 16) {
        unsigned o0 = (unsigned)cols[j];
        unsigned o1 = (unsigned)cols[j + 4];
        unsigned o2 = (unsigned)cols[j + 8];
        unsigned o3 = (unsigned)cols[j + 12];
        uint4 v0 = *(const uint4*)(Hb + o0 + fb);
        uint4 v1 = *(const uint4*)(Hb + o1 + fb);
        uint4 v2 = *(const uint4*)(Hb + o2 + fb);
        uint4 v3 = *(const uint4*)(Hb + o3 + fb);
        const unsigned* u0 = (const unsigned*)&v0;
        const unsigned* u1 = (const unsigned*)&v1;
        const unsigned* u2 = (const unsigned*)&v2;
        const unsigned* u3 = (const unsigned*)&v3;
#pragma unroll
        for (int k = 0; k < 4; ++k) {
            UNPK_ADD(accA[k], u0[k]);
            UNPK_ADD(accB[k], u1[k]);
            UNPK_ADD(accA[k], u2[k]);
            UNPK_ADD(accB[k], u3[k]);
        }
    }
    // 2-deep mid
    for (; j + 4 < e; j += 8) {
        unsigned o0 = (unsigned)cols[j];
        unsigned o1 = (unsigned)cols[j + 4];
        uint4 v0 = *(const uint4*)(Hb + o0 + fb);
        uint4 v1 = *(const uint4*)(Hb + o1 + fb);
        const unsigned* u0 = (const unsigned*)&v0;
        const unsigned* u1 = (const unsigned*)&v1;
#pragma unroll
        for (int k = 0; k < 4; ++k) {
            UNPK_ADD(accA[k], u0[k]);
            UNPK_ADD(accB[k], u1[k]);
        }
    }
    if (j < e) {
        unsigned o0 = (unsigned)cols[j];
        uint4 v0 = *(const uint4*)(Hb + o0 + fb);
        const unsigned* u0 = (const unsigned*)&v0;
#pragma unroll
        for (int k = 0; k < 4; ++k) UNPK_ADD(accA[k], u0[k]);
    }
#undef UNPK_ADD

    float acc[8];
#pragma unroll
    for (int k = 0; k < 4; ++k) {
        acc[2 * k]     = accA[k].x + accB[k].x;
        acc[2 * k + 1] = accA[k].y + accB[k].y;
    }

#pragma unroll
    for (int k = 0; k < 8; ++k) {
        acc[k] += __shfl_xor(acc[k], 16, 64);
        acc[k] += __shfl_xor(acc[k], 32, 64);
    }

    if (q == 0) {
        unsigned f = (lane & 15) << 3;   // feature index (floats/shorts)
        float inv_i = inv[node];
        float4 b0 = *(const float4*)(bias + f);
        float4 b1v = *(const float4*)(bias + f + 4);
        float r[8];
        r[0] = acc[0] * inv_i + b0.x; r[1] = acc[1] * inv_i + b0.y;
        r[2] = acc[2] * inv_i + b0.z; r[3] = acc[3] * inv_i + b0.w;
        r[4] = acc[4] * inv_i + b1v.x; r[5] = acc[5] * inv_i + b1v.y;
        r[6] = acc[6] * inv_i + b1v.z; r[7] = acc[7] * inv_i + b1v.w;
        if (RELU) {
#pragma unroll
            for (int k = 0; k < 8; ++k) r[k] = fmaxf(r[k], 0.f);
        }
        if (EMIT_SPLIT) {
            ushort4 hv[2], lv[2];
#pragma unroll
            for (int g = 0; g < 2; ++g) {
#pragma unroll
                for (int k = 0; k < 4; ++k) {
                    float y = r[g * 4 + k];
                    unsigned u = __float_as_uint(y);
                    unsigned short hb = (unsigned short)(u >> 16);
                    float lo = y - __uint_as_float(u & 0xFFFF0000u);
                    ((unsigned short*)&hv[g])[k] = hb;
                    ((unsigned short*)&lv[g])[k] = f2bf(lo);
                }
            }
            *(ushort4*)(XH + (size_t)node * NFEAT + f)     = hv[0];
            *(ushort4*)(XH + (size_t)node * NFEAT + f + 4) = hv[1];
            *(ushort4*)(XL + (size_t)node * NFEAT + f)     = lv[0];
            *(ushort4*)(XL + (size_t)node * NFEAT + f + 4) = lv[1];
        } else {
            *(float4*)(out + (size_t)node * NFEAT + f)     = make_float4(r[0], r[1], r[2], r[3]);
            *(float4*)(out + (size_t)node * NFEAT + f + 4) = make_float4(r[4], r[5], r[6], r[7]);
        }
    }
}

// ---------------- launch ----------------
static inline size_t align256(size_t x) { return (x + 255) & ~(size_t)255; }

extern "C" void kernel_launch(void* const* d_in, const int* in_sizes, int n_in,
                              void* d_out, int out_size, void* d_ws, size_t ws_size,
                              hipStream_t stream) {
    const float* x   = (const float*)d_in[0];
    const int*   ei  = (const int*)d_in[1];
    const float* W1  = (const float*)d_in[2];
    const float* b1  = (const float*)d_in[3];
    const float* W2  = (const float*)d_in[4];
    const float* b2  = (const float*)d_in[5];
    const float* W3  = (const float*)d_in[6];
    const float* b3  = (const float*)d_in[7];
    float* out = (float*)d_out;

    const int N = in_sizes[0] / NFEAT;
    const int E = in_sizes[1] / 2;
    const int* rows = ei;
    const int* colsIn = ei + E;

    const int nbk = (E + EPB - 1) / EPB;       // edge blocks
    const int nbu = (N + RPB - 1) / RPB;       // row buckets
    const int K = nbk * nbu;

    // workspace layout
    char* ws = (char*)d_ws;
    size_t off = 0;
    unsigned short* Hn = (unsigned short*)(ws + off);
    off = align256(off + (size_t)N * NFEAT * sizeof(unsigned short));
    unsigned short* XH = (unsigned short*)(ws + off);
    off = align256(off + (size_t)N * NFEAT * sizeof(unsigned short));
    unsigned short* XL = (unsigned short*)(ws + off);
    off = align256(off + (size_t)N * NFEAT * sizeof(unsigned short));
    int*   bufA    = (int*)(ws + off);   off = align256(off + (size_t)K * sizeof(int));
    int*   bufB    = (int*)(ws + off);   off = align256(off + (size_t)K * sizeof(int));
    int*   bsums   = (int*)(ws + off);   off = align256(off + (size_t)256 * sizeof(int));
    int*   packed  = (int*)(ws + off);   off = align256(off + (size_t)E * sizeof(int));
    int*   colSort = (int*)(ws + off);   off = align256(off + (size_t)E * sizeof(int));
    int*   row_ptr = (int*)(ws + off);   off = align256(off + (size_t)(N + 1) * sizeof(int));
    float* inv     = (float*)(ws + off); off = align256(off + (size_t)N * sizeof(float));
    unsigned short* WtH = (unsigned short*)(ws + off);
    off = align256(off + (size_t)3 * NFEAT * NFEAT * sizeof(unsigned short));
    unsigned short* WtL = (unsigned short*)(ws + off);
    off = align256(off + (size_t)3 * NFEAT * NFEAT * sizeof(unsigned short));
    (void)ws_size; (void)n_in; (void)out_size;

    const int nb2 = (K + SCAN_B - 1) / SCAN_B;

    // --- W splits (one launch for all 3 layers) ---
    wsplit3_kernel<<<dim3(64, 3), 256, 0, stream>>>(W1, W2, W3, WtH, WtL);

    // --- CSR build (coalesced counting sort) ---
    a1_hist<<<nbk, 256, 0, stream>>>(rows, E, bufA, nbu);
    transpose_counts<<<(K + 255) / 256, 256, 0, stream>>>(bufA, bufB, nbk, nbu);
    scanA_kernel<<<nb2, SCAN_B, 0, stream>>>(bufB, K, bufA, bsums);
    scanB_kernel<<<1, 256, 0, stream>>>(bsums, nb2);
    a2_scatter<<<nbk, 256, 0, stream>>>(rows, colsIn, E, bufA, bsums, nbk, nbu, packed);
    b_sort<<<nbu, 256, 0, stream>>>(packed, bufA, bsums, nbk, nbu, N, E, colSort, row_ptr, inv);

    const int gemm_grid = (N + 63) / 64;
    const int agg_grid  = (N + 3) / 4;

    // --- layer 1 ---
    gemm_mfma_f32<<<gemm_grid, 256, 0, stream>>>(x, WtH, WtL, inv, Hn, N);
    aggregate_bf16<1, 1><<<agg_grid, 256, 0, stream>>>(Hn, row_ptr, colSort, inv, b1,
                                                       nullptr, XH, XL, N);
    // --- layer 2 ---
    gemm_mfma_bf16<<<gemm_grid, 256, 0, stream>>>(XH, XL, WtH + NFEAT * NFEAT, WtL + NFEAT * NFEAT,
                                                  inv, Hn, N);
    aggregate_bf16<1, 1><<<agg_grid, 256, 0, stream>>>(Hn, row_ptr, colSort, inv, b2,
                                                       nullptr, XH, XL, N);
    // --- layer 3 ---
    gemm_mfma_bf16<<<gemm_grid, 256, 0, stream>>>(XH, XL, WtH + 2 * NFEAT * NFEAT,
                                                  WtL + 2 * NFEAT * NFEAT, inv, Hn, N);
    aggregate_bf16<0, 0><<<agg_grid, 256, 0, stream>>>(Hn, row_ptr, colSort, inv, b3,
                                                       out, nullptr, nullptr, N);
}